// Round 1
// baseline (1429.249 us; speedup 1.0000x reference)
//
#include <hip/hip_runtime.h>
#include <math.h>

#define BN_SCALE 0.99999500003749967f
#define RRELU_SLOPE 0.22916666666666666f

static __device__ __forceinline__ float leaky(float v) { return v > 0.f ? v : 0.01f * v; }

// ---------------------------------------------------------------------------
// Fused FeatureExtractor: one block per sequence (4050 blocks, 256 threads).
// conv1(1->32,k3)+bn+leaky+pool2x2 -> (16,186)
// conv2(16->64,k3)+bn+leaky+pool2x2 -> (32,92)
// conv3(32->96,k3)+bn+leaky+pool2x2 -> (48,45)
// flatten(2160) @ fc(2160,32) -> feats row (32)
// ---------------------------------------------------------------------------
__global__ __launch_bounds__(256) void fe_kernel(
    const float* __restrict__ x,
    const float* __restrict__ w1c, const float* __restrict__ b1c,
    const float* __restrict__ g1,  const float* __restrict__ bb1,
    const float* __restrict__ w2c, const float* __restrict__ b2c,
    const float* __restrict__ g2,  const float* __restrict__ bb2,
    const float* __restrict__ w3c, const float* __restrict__ b3c,
    const float* __restrict__ g3,  const float* __restrict__ bb3,
    const float* __restrict__ fcw, const float* __restrict__ fcb,
    float* __restrict__ feats)
{
  __shared__ float s_x[375];
  __shared__ float s1[16][186];
  __shared__ float s2[32][92];
  __shared__ float s3[2160];
  __shared__ float s_w1[32][3];
  __shared__ float s_b1[32];
  __shared__ float s_gs2[64], s_be2[64];
  __shared__ float s_gs3[96], s_be3[96];
  __shared__ float s_part[256];

  const int t = threadIdx.x;
  const int n = blockIdx.x;

  for (int i = t; i < 375; i += 256) s_x[i] = x[n * 375 + i];
  if (t < 32) {
    float gs = g1[t] * BN_SCALE;
    s_w1[t][0] = w1c[t * 3 + 0] * gs;
    s_w1[t][1] = w1c[t * 3 + 1] * gs;
    s_w1[t][2] = w1c[t * 3 + 2] * gs;
    s_b1[t] = b1c[t] * gs + bb1[t];
  }
  if (t < 64) { float gs = g2[t] * BN_SCALE; s_gs2[t] = gs; s_be2[t] = b2c[t] * gs + bb2[t]; }
  if (t < 96) { float gs = g3[t] * BN_SCALE; s_gs3[t] = gs; s_be3[t] = b3c[t] * gs + bb3[t]; }
  __syncthreads();

  // ---- stage 1: conv1 (bn folded into weights) + leaky + 2x2 pool ----
  for (int o = t; o < 16 * 186; o += 256) {
    int c16 = o / 186;
    int l = o - c16 * 186;
    int p = 2 * l;
    float m = -3.4e38f;
#pragma unroll
    for (int dc = 0; dc < 2; ++dc) {
      int c = 2 * c16 + dc;
      float u0 = s_w1[c][0], u1 = s_w1[c][1], u2 = s_w1[c][2], be = s_b1[c];
#pragma unroll
      for (int dp = 0; dp < 2; ++dp) {
        float v = fmaf(s_x[p + dp], u0, fmaf(s_x[p + dp + 1], u1, fmaf(s_x[p + dp + 2], u2, be)));
        m = fmaxf(m, leaky(v));
      }
    }
    s1[c16][l] = m;
  }
  __syncthreads();

  // ---- stage 2: conv2 64ch x 184 pos. lane = position (clamped), channels in regs ----
  {
    const int p = min(t, 183);
    float a[16][3];
#pragma unroll
    for (int ci = 0; ci < 16; ++ci) {
      a[ci][0] = s1[ci][p]; a[ci][1] = s1[ci][p + 1]; a[ci][2] = s1[ci][p + 2];
    }
    const bool act = (t < 184) && ((t & 1) == 0);
#pragma unroll
    for (int chalf = 0; chalf < 2; ++chalf) {
      float acc[32];
#pragma unroll
      for (int cc = 0; cc < 32; ++cc) {
        const int c = chalf * 32 + cc;
        const float4* wp = reinterpret_cast<const float4*>(w2c + c * 48);
        float wv[48];
#pragma unroll
        for (int q = 0; q < 12; ++q) {
          float4 v = wp[q];
          wv[4 * q + 0] = v.x; wv[4 * q + 1] = v.y; wv[4 * q + 2] = v.z; wv[4 * q + 3] = v.w;
        }
        float s = 0.f;
#pragma unroll
        for (int ci = 0; ci < 16; ++ci) {
          s = fmaf(a[ci][0], wv[ci * 3 + 0], s);
          s = fmaf(a[ci][1], wv[ci * 3 + 1], s);
          s = fmaf(a[ci][2], wv[ci * 3 + 2], s);
        }
        acc[cc] = leaky(fmaf(s, s_gs2[c], s_be2[c]));
      }
      // pool: channel pairs in-thread, position pairs via adjacent lanes
#pragma unroll
      for (int u = 0; u < 16; ++u) {
        float m = fmaxf(acc[2 * u], acc[2 * u + 1]);
        m = fmaxf(m, __shfl_xor(m, 1));
        if (act) s2[chalf * 16 + u][t >> 1] = m;
      }
    }
  }
  __syncthreads();

  // ---- stage 3: conv3 96ch x 90 pos. lane = (half h, position), 24-ch register tiles ----
  {
    const int h = __builtin_amdgcn_readfirstlane(t >> 7);  // wave-uniform: 0,0,1,1
    const int pp = t & 127;
    const int p = min(pp, 89);
    const bool act = (pp < 90) && ((pp & 1) == 0);
#pragma unroll
    for (int csub = 0; csub < 2; ++csub) {
      float acc[24];
#pragma unroll
      for (int cc = 0; cc < 24; ++cc) acc[cc] = 0.f;
      for (int half = 0; half < 2; ++half) {   // ci halves: 0..15 / 16..31
        float a[16][3];
#pragma unroll
        for (int ci = 0; ci < 16; ++ci) {
          a[ci][0] = s2[half * 16 + ci][p];
          a[ci][1] = s2[half * 16 + ci][p + 1];
          a[ci][2] = s2[half * 16 + ci][p + 2];
        }
#pragma unroll
        for (int cc = 0; cc < 24; ++cc) {
          const int c = h * 48 + csub * 24 + cc;
          const float4* wp = reinterpret_cast<const float4*>(w3c + c * 96 + half * 48);
          float wv[48];
#pragma unroll
          for (int q = 0; q < 12; ++q) {
            float4 v = wp[q];
            wv[4 * q + 0] = v.x; wv[4 * q + 1] = v.y; wv[4 * q + 2] = v.z; wv[4 * q + 3] = v.w;
          }
          float s = 0.f;
#pragma unroll
          for (int ci = 0; ci < 16; ++ci) {
            s = fmaf(a[ci][0], wv[ci * 3 + 0], s);
            s = fmaf(a[ci][1], wv[ci * 3 + 1], s);
            s = fmaf(a[ci][2], wv[ci * 3 + 2], s);
          }
          acc[cc] += s;
        }
      }
#pragma unroll
      for (int cc = 0; cc < 24; ++cc) {
        const int c = h * 48 + csub * 24 + cc;
        acc[cc] = leaky(fmaf(acc[cc], s_gs3[c], s_be3[c]));
      }
#pragma unroll
      for (int u = 0; u < 12; ++u) {
        float m = fmaxf(acc[2 * u], acc[2 * u + 1]);
        m = fmaxf(m, __shfl_xor(m, 1));
        int ug = h * 24 + csub * 12 + u;   // pooled channel
        if (act) s3[ug * 45 + (pp >> 1)] = m;
      }
    }
  }
  __syncthreads();

  // ---- FC: 32 outputs, 8 k-groups of 270 ----
  {
    const int j = t & 31;
    const int s = t >> 5;
    float sum = 0.f;
    const int k0 = s * 270;
#pragma unroll 2
    for (int k = k0; k < k0 + 270; ++k)
      sum = fmaf(s3[k], fcw[k * 32 + j], sum);
    s_part[t] = sum;
    __syncthreads();
    if (t < 32) {
      float tot = fcb[t];
#pragma unroll
      for (int q = 0; q < 8; ++q) tot += s_part[q * 32 + t];
      feats[n * 32 + t] = tot;
    }
  }
}

// ---------------------------------------------------------------------------
// Similarity MLP: one thread per (subject, pair) row. 30*9045 = 271350 rows.
// ---------------------------------------------------------------------------
__global__ __launch_bounds__(256) void sim_kernel(
    const float* __restrict__ feats,
    const float* __restrict__ w1, const float* __restrict__ b1,
    const float* __restrict__ w2, const float* __restrict__ b2,
    const float* __restrict__ w3, const float* __restrict__ b3,
    const float* __restrict__ w4, const float* __restrict__ b4,
    float* __restrict__ subjects)
{
  const int idx = blockIdx.x * 256 + threadIdx.x;
  if (idx >= 30 * 9045) return;
  const int b = idx / 9045;
  const int p = idx - b * 9045;

  // decode (i,j) from triu pair index p: S(i) = 134*i - i*(i-1)/2
  int i = (int)((269.0f - sqrtf((float)(72361 - 8 * p))) * 0.5f);
  i = max(0, min(133, i));
  while (134 * (i + 1) - ((i + 1) * i) / 2 <= p) ++i;
  while (134 * i - (i * (i - 1)) / 2 > p) --i;
  const int j = i + 1 + (p - (134 * i - (i * (i - 1)) / 2));

  const float4* f1 = reinterpret_cast<const float4*>(feats + (b * 135 + i) * 32);
  const float4* f2 = reinterpret_cast<const float4*>(feats + (b * 135 + j) * 32);
  float in[64];
#pragma unroll
  for (int q = 0; q < 8; ++q) {
    float4 v = f1[q];
    in[4 * q + 0] = v.x; in[4 * q + 1] = v.y; in[4 * q + 2] = v.z; in[4 * q + 3] = v.w;
  }
#pragma unroll
  for (int q = 0; q < 8; ++q) {
    float4 v = f2[q];
    in[32 + 4 * q + 0] = v.x; in[32 + 4 * q + 1] = v.y; in[32 + 4 * q + 2] = v.z; in[32 + 4 * q + 3] = v.w;
  }

  float h1[32];
#pragma unroll
  for (int jj = 0; jj < 32; ++jj) h1[jj] = b1[jj];
#pragma unroll
  for (int ii = 0; ii < 64; ++ii) {
    float av = in[ii];
#pragma unroll
    for (int jj = 0; jj < 32; ++jj) h1[jj] = fmaf(av, w1[ii * 32 + jj], h1[jj]);
  }
#pragma unroll
  for (int jj = 0; jj < 32; ++jj) h1[jj] = fmaxf(h1[jj], 0.f);

  float h2[16];
#pragma unroll
  for (int jj = 0; jj < 16; ++jj) h2[jj] = b2[jj];
#pragma unroll
  for (int ii = 0; ii < 32; ++ii) {
    float av = h1[ii];
#pragma unroll
    for (int jj = 0; jj < 16; ++jj) h2[jj] = fmaf(av, w2[ii * 16 + jj], h2[jj]);
  }
#pragma unroll
  for (int jj = 0; jj < 16; ++jj) h2[jj] = fmaxf(h2[jj], 0.f);

  float h3[8];
#pragma unroll
  for (int jj = 0; jj < 8; ++jj) h3[jj] = b3[jj];
#pragma unroll
  for (int ii = 0; ii < 16; ++ii) {
    float av = h2[ii];
#pragma unroll
    for (int jj = 0; jj < 8; ++jj) h3[jj] = fmaf(av, w3[ii * 8 + jj], h3[jj]);
  }
#pragma unroll
  for (int jj = 0; jj < 8; ++jj) h3[jj] = fmaxf(h3[jj], 0.f);

  float z = b4[0];
#pragma unroll
  for (int ii = 0; ii < 8; ++ii) z = fmaf(h3[ii], w4[ii], z);

  // tanh via exp
  float az = fabsf(z);
  float e = __expf(-2.f * az);
  float r = (1.f - e) / (1.f + e);
  subjects[idx] = copysignf(r, z);
}

// ---------------------------------------------------------------------------
// cls layer 1 (30x9045 @ 9045x1024), split over 64 k-chunks -> partials in ws
// ---------------------------------------------------------------------------
__global__ __launch_bounds__(512) void c1_kernel(
    const float* __restrict__ subjects,
    const float* __restrict__ w1,
    float* __restrict__ part)
{
  const int q = blockIdx.x;
  const int t = threadIdx.x;
  const int col = 2 * t;
  const int k0 = q * 142;
  const int k1 = min(9045, k0 + 142);
  float2 acc[30];
#pragma unroll
  for (int r = 0; r < 30; ++r) { acc[r].x = 0.f; acc[r].y = 0.f; }
  for (int k = k0; k < k1; ++k) {
    const float2 w = *reinterpret_cast<const float2*>(w1 + k * 1024 + col);
#pragma unroll
    for (int r = 0; r < 30; ++r) {
      float sv = subjects[r * 9045 + k];
      acc[r].x = fmaf(sv, w.x, acc[r].x);
      acc[r].y = fmaf(sv, w.y, acc[r].y);
    }
  }
#pragma unroll
  for (int r = 0; r < 30; ++r) {
    part[(q * 30 + r) * 1024 + col + 0] = acc[r].x;
    part[(q * 30 + r) * 1024 + col + 1] = acc[r].y;
  }
}

// ---------------------------------------------------------------------------
// cls tail: reduce partials + rrelu, then 1024->256->64->3 + log_softmax.
// One block per subject row.
// ---------------------------------------------------------------------------
__global__ __launch_bounds__(256) void cls_tail_kernel(
    const float* __restrict__ part,
    const float* __restrict__ cb1,
    const float* __restrict__ w2, const float* __restrict__ cb2,
    const float* __restrict__ w3, const float* __restrict__ cb3,
    const float* __restrict__ w4, const float* __restrict__ cb4,
    float* __restrict__ out)
{
  __shared__ float sc1[1024];
  __shared__ float sc2[256];
  __shared__ float sc3[64];
  __shared__ float slg[3];
  const int r = blockIdx.x, t = threadIdx.x;

  for (int j = t; j < 1024; j += 256) {
    float s = cb1[j];
    for (int q = 0; q < 64; ++q) s += part[(q * 30 + r) * 1024 + j];
    sc1[j] = s >= 0.f ? s : RRELU_SLOPE * s;
  }
  __syncthreads();
  {
    float acc = cb2[t];
    for (int kk = 0; kk < 1024; kk += 4) {
      float4 a = *reinterpret_cast<const float4*>(&sc1[kk]);
      acc = fmaf(a.x, w2[(kk + 0) * 256 + t], acc);
      acc = fmaf(a.y, w2[(kk + 1) * 256 + t], acc);
      acc = fmaf(a.z, w2[(kk + 2) * 256 + t], acc);
      acc = fmaf(a.w, w2[(kk + 3) * 256 + t], acc);
    }
    sc2[t] = fmaxf(acc, 0.f);
  }
  __syncthreads();
  if (t < 64) {
    float acc = cb3[t];
#pragma unroll 4
    for (int kk = 0; kk < 256; ++kk) acc = fmaf(sc2[kk], w3[kk * 64 + t], acc);
    sc3[t] = fmaxf(acc, 0.f);
  }
  __syncthreads();
  if (t < 3) {
    float acc = cb4[t];
#pragma unroll
    for (int kk = 0; kk < 64; ++kk) acc = fmaf(sc3[kk], w4[kk * 3 + t], acc);
    slg[t] = acc;
  }
  __syncthreads();
  if (t == 0) {
    float m = fmaxf(slg[0], fmaxf(slg[1], slg[2]));
    float se = __expf(slg[0] - m) + __expf(slg[1] - m) + __expf(slg[2] - m);
    float lse = m + logf(se);
    out[r * 3 + 0] = slg[0] - lse;
    out[r * 3 + 1] = slg[1] - lse;
    out[r * 3 + 2] = slg[2] - lse;
  }
}

extern "C" void kernel_launch(void* const* d_in, const int* in_sizes, int n_in,
                              void* d_out, int out_size, void* d_ws, size_t ws_size,
                              hipStream_t stream) {
  const float* x    = (const float*)d_in[0];
  const float* w1c  = (const float*)d_in[1];
  const float* b1c  = (const float*)d_in[2];
  const float* g1   = (const float*)d_in[3];
  const float* bb1  = (const float*)d_in[4];
  const float* w2c  = (const float*)d_in[5];
  const float* b2c  = (const float*)d_in[6];
  const float* g2   = (const float*)d_in[7];
  const float* bb2  = (const float*)d_in[8];
  const float* w3c  = (const float*)d_in[9];
  const float* b3c  = (const float*)d_in[10];
  const float* g3   = (const float*)d_in[11];
  const float* bb3  = (const float*)d_in[12];
  const float* fcw  = (const float*)d_in[13];
  const float* fcb  = (const float*)d_in[14];
  const float* sw1  = (const float*)d_in[15];
  const float* sb1  = (const float*)d_in[16];
  const float* sw2  = (const float*)d_in[17];
  const float* sb2  = (const float*)d_in[18];
  const float* sw3  = (const float*)d_in[19];
  const float* sb3  = (const float*)d_in[20];
  const float* sw4  = (const float*)d_in[21];
  const float* sb4  = (const float*)d_in[22];
  const float* cw1  = (const float*)d_in[23];
  const float* cb1  = (const float*)d_in[24];
  const float* cw2  = (const float*)d_in[25];
  const float* cb2  = (const float*)d_in[26];
  const float* cw3  = (const float*)d_in[27];
  const float* cb3  = (const float*)d_in[28];
  const float* cw4  = (const float*)d_in[29];
  const float* cb4  = (const float*)d_in[30];

  float* ws = (float*)d_ws;
  float* feats    = ws;                 // 4050*32      = 129600 floats
  float* subjects = ws + 129600;        // 30*9045      = 271350 floats
  float* part     = ws + 401408;        // 64*30*1024   = 1966080 floats (~9.5 MB total)

  fe_kernel<<<4050, 256, 0, stream>>>(x, w1c, b1c, g1, bb1, w2c, b2c, g2, bb2,
                                      w3c, b3c, g3, bb3, fcw, fcb, feats);
  sim_kernel<<<1060, 256, 0, stream>>>(feats, sw1, sb1, sw2, sb2, sw3, sb3, sw4, sb4, subjects);
  c1_kernel<<<64, 512, 0, stream>>>(subjects, cw1, part);
  cls_tail_kernel<<<30, 256, 0, stream>>>(part, cb1, cw2, cb2, cw3, cb3, cw4, cb4, (float*)d_out);
}

// Round 2
// 546.272 us; speedup vs baseline: 2.6164x; 2.6164x over previous
//
#include <hip/hip_runtime.h>
#include <math.h>

#define BN_SCALE 0.99999500003749967f
#define RRELU_SLOPE 0.22916666666666666f

static __device__ __forceinline__ float leaky(float v) { return v > 0.f ? v : 0.01f * v; }

// ---------------------------------------------------------------------------
// Fused FeatureExtractor: one block per sequence (4050 blocks, 256 threads).
// Weights in registers, activations stream from LDS (transposed, broadcast).
// ---------------------------------------------------------------------------
__global__ __launch_bounds__(256) void fe_kernel(
    const float* __restrict__ x,
    const float* __restrict__ w1c, const float* __restrict__ b1c,
    const float* __restrict__ g1,  const float* __restrict__ bb1,
    const float* __restrict__ w2c, const float* __restrict__ b2c,
    const float* __restrict__ g2,  const float* __restrict__ bb2,
    const float* __restrict__ w3c, const float* __restrict__ b3c,
    const float* __restrict__ g3,  const float* __restrict__ bb3,
    const float* __restrict__ fcw, const float* __restrict__ fcb,
    float* __restrict__ feats)
{
  __shared__ float s_x[375];
  __shared__ float s1t[186 * 16];   // [pos][ch] transposed
  __shared__ float s2t[92 * 32];    // [pos][ch] transposed
  __shared__ float s3[2160];        // flat ch*45+pos (FC layout)
  __shared__ float s_w1[32 * 3];
  __shared__ float s_b1[32];
  __shared__ float s_gs2[64], s_be2[64];
  __shared__ float s_gs3[96], s_be3[96];
  __shared__ float s_part[16 * 32];

  const int t = threadIdx.x;
  const int n = blockIdx.x;

  for (int i = t; i < 375; i += 256) s_x[i] = x[n * 375 + i];
  if (t < 32) {
    float gs = g1[t] * BN_SCALE;
    s_w1[t * 3 + 0] = w1c[t * 3 + 0] * gs;
    s_w1[t * 3 + 1] = w1c[t * 3 + 1] * gs;
    s_w1[t * 3 + 2] = w1c[t * 3 + 2] * gs;
    s_b1[t] = b1c[t] * gs + bb1[t];
  }
  if (t < 64) { float gs = g2[t] * BN_SCALE; s_gs2[t] = gs; s_be2[t] = b2c[t] * gs + bb2[t]; }
  if (t < 96) { float gs = g3[t] * BN_SCALE; s_gs3[t] = gs; s_be3[t] = b3c[t] * gs + bb3[t]; }
  __syncthreads();

  // ---- stage 1: conv1+bn+leaky+pool -> s1t[pos][16] ----
  for (int o = t; o < 16 * 186; o += 256) {
    const int c16 = o & 15;
    const int l = o >> 4;
    const int p = 2 * l;
    float m = -3.4e38f;
#pragma unroll
    for (int dc = 0; dc < 2; ++dc) {
      const int c = 2 * c16 + dc;
      const float u0 = s_w1[c * 3 + 0], u1 = s_w1[c * 3 + 1], u2 = s_w1[c * 3 + 2];
      const float be = s_b1[c];
#pragma unroll
      for (int dp = 0; dp < 2; ++dp) {
        float v = fmaf(s_x[p + dp], u0, fmaf(s_x[p + dp + 1], u1, fmaf(s_x[p + dp + 2], u2, be)));
        m = fmaxf(m, leaky(v));
      }
    }
    s1t[l * 16 + c16] = m;
  }
  __syncthreads();

  // ---- stage 2: conv2(16->64)+bn+leaky+pool -> s2t[pos][32] ----
  // thread = (channel c = t&63, pos-group g = t>>6); weights in regs.
  {
    const int c = t & 63;
    const int g = t >> 6;
    const float gs = s_gs2[c];
    const float be = s_be2[c];
    float wv[48];
    {
      const float4* wp = reinterpret_cast<const float4*>(w2c + c * 48);
#pragma unroll
      for (int q = 0; q < 12; ++q) {
        float4 v = wp[q];
        wv[4 * q + 0] = v.x * gs; wv[4 * q + 1] = v.y * gs;
        wv[4 * q + 2] = v.z * gs; wv[4 * q + 3] = v.w * gs;
      }
    }
    float a0 = be, a1 = be, a2 = be;
    float prev = 0.f;
    const int base = 46 * g;   // input/output column base for this group
#pragma unroll 4
    for (int q = 0; q < 48; ++q) {
      const float4* cp = reinterpret_cast<const float4*>(&s1t[(base + q) * 16]);
      float4 c0 = cp[0], c1 = cp[1], c2 = cp[2], c3 = cp[3];
      float col[16] = {c0.x, c0.y, c0.z, c0.w, c1.x, c1.y, c1.z, c1.w,
                       c2.x, c2.y, c2.z, c2.w, c3.x, c3.y, c3.z, c3.w};
#pragma unroll
      for (int ci = 0; ci < 16; ++ci) {
        a2 = fmaf(wv[ci * 3 + 2], col[ci], a2);
        a1 = fmaf(wv[ci * 3 + 1], col[ci], a1);
        a0 = fmaf(wv[ci * 3 + 0], col[ci], a0);
      }
      if (q >= 2) {
        const int P = q - 2;             // local output pos 0..45
        const float v = leaky(a2);
        if (P & 1) {
          float m = fmaxf(prev, v);
          m = fmaxf(m, __shfl_xor(m, 1));          // channel pair c^1
          if ((c & 1) == 0) s2t[(23 * g + (P >> 1)) * 32 + (c >> 1)] = m;
        } else prev = v;
      }
      a2 = a1; a1 = a0; a0 = be;
    }
  }
  __syncthreads();

  // ---- stage 3: conv3(32->96)+bn+leaky+pool -> s3[ch*45+pos] ----
  // thread t<192: channel c = t>>1 (0..95), ci-half = t&1; weights in regs.
  if (t < 192) {
    const int c = t >> 1;
    const int half = t & 1;
    const float gs = s_gs3[c];
    const float be = s_be3[c];
    float wv[48];
    {
      const float4* wp = reinterpret_cast<const float4*>(w3c + c * 96 + half * 48);
#pragma unroll
      for (int q = 0; q < 12; ++q) {
        float4 v = wp[q];
        wv[4 * q + 0] = v.x * gs; wv[4 * q + 1] = v.y * gs;
        wv[4 * q + 2] = v.z * gs; wv[4 * q + 3] = v.w * gs;
      }
    }
    float a0 = 0.f, a1 = 0.f, a2 = 0.f;
    float prev = 0.f;
#pragma unroll 4
    for (int q = 0; q < 92; ++q) {
      const float4* cp = reinterpret_cast<const float4*>(&s2t[q * 32 + half * 16]);
      float4 c0 = cp[0], c1 = cp[1], c2 = cp[2], c3 = cp[3];
      float col[16] = {c0.x, c0.y, c0.z, c0.w, c1.x, c1.y, c1.z, c1.w,
                       c2.x, c2.y, c2.z, c2.w, c3.x, c3.y, c3.z, c3.w};
#pragma unroll
      for (int ci = 0; ci < 16; ++ci) {
        a2 = fmaf(wv[ci * 3 + 2], col[ci], a2);
        a1 = fmaf(wv[ci * 3 + 1], col[ci], a1);
        a0 = fmaf(wv[ci * 3 + 0], col[ci], a0);
      }
      if (q >= 2) {
        const int P = q - 2;             // output pos 0..89
        float v = a2 + __shfl_xor(a2, 1);          // combine ci halves
        v = leaky(v + be);
        if (P & 1) {
          float m = fmaxf(prev, v);
          m = fmaxf(m, __shfl_xor(m, 2));          // channel pair (lanes differ by 2)
          if ((t & 3) == 0) s3[(c >> 1) * 45 + (P >> 1)] = m;
        } else prev = v;
      }
      a2 = a1; a1 = a0; a0 = 0.f;
    }
  }
  __syncthreads();

  // ---- FC: 2160 -> 32. thread = (col-pair j2 = t&15, k-group s = t>>4) ----
  {
    const int j2 = t & 15;
    const int s = t >> 4;
    const int k0 = s * 135;
    float2 acc; acc.x = 0.f; acc.y = 0.f;
#pragma unroll 4
    for (int i = 0; i < 135; ++i) {
      const int k = k0 + i;
      const float sv = s3[k];
      const float2 w = *reinterpret_cast<const float2*>(fcw + k * 32 + 2 * j2);
      acc.x = fmaf(sv, w.x, acc.x);
      acc.y = fmaf(sv, w.y, acc.y);
    }
    s_part[s * 32 + 2 * j2 + 0] = acc.x;
    s_part[s * 32 + 2 * j2 + 1] = acc.y;
  }
  __syncthreads();
  if (t < 32) {
    float tot = fcb[t];
#pragma unroll
    for (int s = 0; s < 16; ++s) tot += s_part[s * 32 + t];
    feats[n * 32 + t] = tot;
  }
}

// ---------------------------------------------------------------------------
// Similarity MLP: one thread per (subject, pair) row; weights staged in LDS.
// ---------------------------------------------------------------------------
__global__ __launch_bounds__(256) void sim_kernel(
    const float* __restrict__ feats,
    const float* __restrict__ w1, const float* __restrict__ b1,
    const float* __restrict__ w2, const float* __restrict__ b2,
    const float* __restrict__ w3, const float* __restrict__ b3,
    const float* __restrict__ w4, const float* __restrict__ b4,
    float* __restrict__ subjects)
{
  __shared__ float sw1[64 * 32];
  __shared__ float sw2[32 * 16];
  __shared__ float sw3[16 * 8];
  __shared__ float sw4[8];
  __shared__ float sb1[32], sb2[16], sb3[8], sb4[1];

  const int t = threadIdx.x;
  for (int i = t; i < 2048; i += 256) sw1[i] = w1[i];
  for (int i = t; i < 512; i += 256) sw2[i] = w2[i];
  if (t < 128) sw3[t] = w3[t];
  if (t < 8) sw4[t] = w4[t];
  if (t < 32) sb1[t] = b1[t];
  if (t < 16) sb2[t] = b2[t];
  if (t < 8) sb3[t] = b3[t];
  if (t == 0) sb4[0] = b4[0];
  __syncthreads();

  const int idx = blockIdx.x * 256 + t;
  if (idx >= 30 * 9045) return;
  const int b = idx / 9045;
  const int p = idx - b * 9045;

  // decode (i,j) from triu pair index p: S(i) = 134*i - i*(i-1)/2
  int i = (int)((269.0f - sqrtf((float)(72361 - 8 * p))) * 0.5f);
  i = max(0, min(133, i));
  while (134 * (i + 1) - ((i + 1) * i) / 2 <= p) ++i;
  while (134 * i - (i * (i - 1)) / 2 > p) --i;
  const int j = i + 1 + (p - (134 * i - (i * (i - 1)) / 2));

  const float4* f1 = reinterpret_cast<const float4*>(feats + (b * 135 + i) * 32);
  const float4* f2 = reinterpret_cast<const float4*>(feats + (b * 135 + j) * 32);
  float in[64];
#pragma unroll
  for (int q = 0; q < 8; ++q) {
    float4 v = f1[q];
    in[4 * q + 0] = v.x; in[4 * q + 1] = v.y; in[4 * q + 2] = v.z; in[4 * q + 3] = v.w;
  }
#pragma unroll
  for (int q = 0; q < 8; ++q) {
    float4 v = f2[q];
    in[32 + 4 * q + 0] = v.x; in[32 + 4 * q + 1] = v.y; in[32 + 4 * q + 2] = v.z; in[32 + 4 * q + 3] = v.w;
  }

  float h1[32];
#pragma unroll
  for (int jj = 0; jj < 32; ++jj) h1[jj] = sb1[jj];
#pragma unroll 8
  for (int ii = 0; ii < 64; ++ii) {
    const float av = in[ii];
    const float4* wr = reinterpret_cast<const float4*>(&sw1[ii * 32]);
#pragma unroll
    for (int r = 0; r < 8; ++r) {
      float4 w = wr[r];
      h1[4 * r + 0] = fmaf(av, w.x, h1[4 * r + 0]);
      h1[4 * r + 1] = fmaf(av, w.y, h1[4 * r + 1]);
      h1[4 * r + 2] = fmaf(av, w.z, h1[4 * r + 2]);
      h1[4 * r + 3] = fmaf(av, w.w, h1[4 * r + 3]);
    }
  }
#pragma unroll
  for (int jj = 0; jj < 32; ++jj) h1[jj] = fmaxf(h1[jj], 0.f);

  float h2[16];
#pragma unroll
  for (int jj = 0; jj < 16; ++jj) h2[jj] = sb2[jj];
#pragma unroll 8
  for (int ii = 0; ii < 32; ++ii) {
    const float av = h1[ii];
    const float4* wr = reinterpret_cast<const float4*>(&sw2[ii * 16]);
#pragma unroll
    for (int r = 0; r < 4; ++r) {
      float4 w = wr[r];
      h2[4 * r + 0] = fmaf(av, w.x, h2[4 * r + 0]);
      h2[4 * r + 1] = fmaf(av, w.y, h2[4 * r + 1]);
      h2[4 * r + 2] = fmaf(av, w.z, h2[4 * r + 2]);
      h2[4 * r + 3] = fmaf(av, w.w, h2[4 * r + 3]);
    }
  }
#pragma unroll
  for (int jj = 0; jj < 16; ++jj) h2[jj] = fmaxf(h2[jj], 0.f);

  float h3[8];
#pragma unroll
  for (int jj = 0; jj < 8; ++jj) h3[jj] = sb3[jj];
#pragma unroll
  for (int ii = 0; ii < 16; ++ii) {
    const float av = h2[ii];
    const float4* wr = reinterpret_cast<const float4*>(&sw3[ii * 8]);
#pragma unroll
    for (int r = 0; r < 2; ++r) {
      float4 w = wr[r];
      h3[4 * r + 0] = fmaf(av, w.x, h3[4 * r + 0]);
      h3[4 * r + 1] = fmaf(av, w.y, h3[4 * r + 1]);
      h3[4 * r + 2] = fmaf(av, w.z, h3[4 * r + 2]);
      h3[4 * r + 3] = fmaf(av, w.w, h3[4 * r + 3]);
    }
  }
#pragma unroll
  for (int jj = 0; jj < 8; ++jj) h3[jj] = fmaxf(h3[jj], 0.f);

  float z = sb4[0];
#pragma unroll
  for (int ii = 0; ii < 8; ++ii) z = fmaf(h3[ii], sw4[ii], z);

  float az = fabsf(z);
  float e = __expf(-2.f * az);
  float r = (1.f - e) / (1.f + e);
  subjects[idx] = copysignf(r, z);
}

// ---------------------------------------------------------------------------
// cls layer 1: 128 blocks = 64 k-chunks x 2 col-halves; subjects staged in LDS.
// ---------------------------------------------------------------------------
__global__ __launch_bounds__(256) void c1_kernel(
    const float* __restrict__ subjects,
    const float* __restrict__ w1,
    float* __restrict__ part)
{
  __shared__ float s_sub[30 * 142];
  const int q = blockIdx.x >> 1;
  const int g = blockIdx.x & 1;
  const int t = threadIdx.x;
  const int k0 = q * 142;
  const int nk = min(9045, k0 + 142) - k0;

  for (int idx = t; idx < 30 * nk; idx += 256) {
    const int r = idx / nk;
    const int kk = idx - r * nk;
    s_sub[r * 142 + kk] = subjects[r * 9045 + k0 + kk];
  }
  __syncthreads();

  const int col = g * 512 + 2 * t;
  float2 acc[30];
#pragma unroll
  for (int r = 0; r < 30; ++r) { acc[r].x = 0.f; acc[r].y = 0.f; }
  for (int kk = 0; kk < nk; ++kk) {
    const float2 w = *reinterpret_cast<const float2*>(w1 + (size_t)(k0 + kk) * 1024 + col);
#pragma unroll
    for (int r = 0; r < 30; ++r) {
      const float sv = s_sub[r * 142 + kk];
      acc[r].x = fmaf(sv, w.x, acc[r].x);
      acc[r].y = fmaf(sv, w.y, acc[r].y);
    }
  }
#pragma unroll
  for (int r = 0; r < 30; ++r) {
    part[(q * 30 + r) * 1024 + col + 0] = acc[r].x;
    part[(q * 30 + r) * 1024 + col + 1] = acc[r].y;
  }
}

// ---------------------------------------------------------------------------
// cls tail: reduce partials + rrelu, then 1024->256->64->3 + log_softmax.
// ---------------------------------------------------------------------------
__global__ __launch_bounds__(256) void cls_tail_kernel(
    const float* __restrict__ part,
    const float* __restrict__ cb1,
    const float* __restrict__ w2, const float* __restrict__ cb2,
    const float* __restrict__ w3, const float* __restrict__ cb3,
    const float* __restrict__ w4, const float* __restrict__ cb4,
    float* __restrict__ out)
{
  __shared__ float sc1[1024];
  __shared__ float sc2[256];
  __shared__ float sc3[64];
  __shared__ float slg[3];
  const int r = blockIdx.x, t = threadIdx.x;

  for (int j = t; j < 1024; j += 256) {
    float s = cb1[j];
    for (int q = 0; q < 64; ++q) s += part[(q * 30 + r) * 1024 + j];
    sc1[j] = s >= 0.f ? s : RRELU_SLOPE * s;
  }
  __syncthreads();
  {
    float acc = cb2[t];
    for (int kk = 0; kk < 1024; kk += 4) {
      float4 a = *reinterpret_cast<const float4*>(&sc1[kk]);
      acc = fmaf(a.x, w2[(kk + 0) * 256 + t], acc);
      acc = fmaf(a.y, w2[(kk + 1) * 256 + t], acc);
      acc = fmaf(a.z, w2[(kk + 2) * 256 + t], acc);
      acc = fmaf(a.w, w2[(kk + 3) * 256 + t], acc);
    }
    sc2[t] = fmaxf(acc, 0.f);
  }
  __syncthreads();
  if (t < 64) {
    float acc = cb3[t];
#pragma unroll 4
    for (int kk = 0; kk < 256; ++kk) acc = fmaf(sc2[kk], w3[kk * 64 + t], acc);
    sc3[t] = fmaxf(acc, 0.f);
  }
  __syncthreads();
  if (t < 3) {
    float acc = cb4[t];
#pragma unroll
    for (int kk = 0; kk < 64; ++kk) acc = fmaf(sc3[kk], w4[kk * 3 + t], acc);
    slg[t] = acc;
  }
  __syncthreads();
  if (t == 0) {
    float m = fmaxf(slg[0], fmaxf(slg[1], slg[2]));
    float se = __expf(slg[0] - m) + __expf(slg[1] - m) + __expf(slg[2] - m);
    float lse = m + logf(se);
    out[r * 3 + 0] = slg[0] - lse;
    out[r * 3 + 1] = slg[1] - lse;
    out[r * 3 + 2] = slg[2] - lse;
  }
}

extern "C" void kernel_launch(void* const* d_in, const int* in_sizes, int n_in,
                              void* d_out, int out_size, void* d_ws, size_t ws_size,
                              hipStream_t stream) {
  const float* x    = (const float*)d_in[0];
  const float* w1c  = (const float*)d_in[1];
  const float* b1c  = (const float*)d_in[2];
  const float* g1   = (const float*)d_in[3];
  const float* bb1  = (const float*)d_in[4];
  const float* w2c  = (const float*)d_in[5];
  const float* b2c  = (const float*)d_in[6];
  const float* g2   = (const float*)d_in[7];
  const float* bb2  = (const float*)d_in[8];
  const float* w3c  = (const float*)d_in[9];
  const float* b3c  = (const float*)d_in[10];
  const float* g3   = (const float*)d_in[11];
  const float* bb3  = (const float*)d_in[12];
  const float* fcw  = (const float*)d_in[13];
  const float* fcb  = (const float*)d_in[14];
  const float* sw1  = (const float*)d_in[15];
  const float* sb1  = (const float*)d_in[16];
  const float* sw2  = (const float*)d_in[17];
  const float* sb2  = (const float*)d_in[18];
  const float* sw3  = (const float*)d_in[19];
  const float* sb3  = (const float*)d_in[20];
  const float* sw4  = (const float*)d_in[21];
  const float* sb4  = (const float*)d_in[22];
  const float* cw1  = (const float*)d_in[23];
  const float* cb1  = (const float*)d_in[24];
  const float* cw2  = (const float*)d_in[25];
  const float* cb2  = (const float*)d_in[26];
  const float* cw3  = (const float*)d_in[27];
  const float* cb3  = (const float*)d_in[28];
  const float* cw4  = (const float*)d_in[29];
  const float* cb4  = (const float*)d_in[30];

  float* ws = (float*)d_ws;
  float* feats    = ws;                 // 4050*32      = 129600 floats
  float* subjects = ws + 129600;        // 30*9045      = 271350 floats
  float* part     = ws + 401408;        // 64*30*1024   = 1966080 floats

  fe_kernel<<<4050, 256, 0, stream>>>(x, w1c, b1c, g1, bb1, w2c, b2c, g2, bb2,
                                      w3c, b3c, g3, bb3, fcw, fcb, feats);
  sim_kernel<<<1060, 256, 0, stream>>>(feats, sw1, sb1, sw2, sb2, sw3, sb3, sw4, sb4, subjects);
  c1_kernel<<<128, 256, 0, stream>>>(subjects, cw1, part);
  cls_tail_kernel<<<30, 256, 0, stream>>>(part, cb1, cw2, cb2, cw3, cb3, cw4, cb4, (float*)d_out);
}

// Round 3
// 463.282 us; speedup vs baseline: 3.0851x; 1.1791x over previous
//
#include <hip/hip_runtime.h>
#include <math.h>

#define BN_SCALE 0.99999500003749967f
#define RRELU_SLOPE 0.22916666666666666f

static __device__ __forceinline__ float leaky(float v) { return v > 0.f ? v : 0.01f * v; }

typedef __attribute__((ext_vector_type(8))) short bf16x8;
typedef __attribute__((ext_vector_type(4))) float f32x4;

static __device__ __forceinline__ unsigned short f2bf(float f) {
  unsigned u = __builtin_bit_cast(unsigned, f);
  u = (u + 0x7FFFu + ((u >> 16) & 1u)) >> 16;
  return (unsigned short)u;
}

// ---------------------------------------------------------------------------
// Fused FeatureExtractor, MFMA edition. One block per sequence, 256 thr.
// conv1 fp32 VALU -> im2col bf16 (Bt2 [192][72])
// conv2 = MFMA A(64x48)*B(48x184) -> pool -> im2col bf16 (Bt3 [96][104])
// conv3 = MFMA A(96x96)*B(96x90)  -> pool -> s3 fp32 [2160] -> FC fp32
// LDS phases overlap via one 40 KB arena (barriers separate lifetimes).
// ---------------------------------------------------------------------------
__global__ __launch_bounds__(256) void fe_kernel(
    const float* __restrict__ x,
    const float* __restrict__ w1c, const float* __restrict__ b1c,
    const float* __restrict__ g1,  const float* __restrict__ bb1,
    const float* __restrict__ w2c, const float* __restrict__ b2c,
    const float* __restrict__ g2,  const float* __restrict__ bb2,
    const float* __restrict__ w3c, const float* __restrict__ b3c,
    const float* __restrict__ g3,  const float* __restrict__ bb3,
    const float* __restrict__ fcw, const float* __restrict__ fcb,
    float* __restrict__ feats)
{
  __shared__ __align__(16) char smem[40960];
  __shared__ float s_w1f[96], s_b1f[32], s_be2[64], s_be3[96], s_part[512];

  const int t = threadIdx.x;
  const int n = blockIdx.x;
  const int wv = t >> 6;
  const int lane = t & 63;
  const int quad = lane >> 4;
  const int lr = lane & 15;

  float* sxf = (float*)(smem);                              // [375] fp32 (phase A)
  unsigned short* bt2 = (unsigned short*)(smem + 1536);     // [192][72] bf16
  unsigned short* w2a = (unsigned short*)(smem + 29184);    // [64][72] bf16
  unsigned short* bt3 = (unsigned short*)(smem);            // [96][104] bf16 (phase C)
  unsigned short* a3s = (unsigned short*)(smem + 19968);    // [96][104] bf16
  float* s3f = (float*)(smem);                              // [2160] fp32 (phase E)

  // ---- phase A: load x, zero Bt2+w2a, fold bn params ----
  for (int i = t; i < 375; i += 256) sxf[i] = x[n * 375 + i];
  {
    float4 z4 = {0.f, 0.f, 0.f, 0.f};
    float4* z = (float4*)(smem + 1536);          // Bt2 (27648B) + w2a (9216B) contiguous
    for (int i = t; i < 2304; i += 256) z[i] = z4;
  }
  if (t < 32) {
    float gs = g1[t] * BN_SCALE;
    s_w1f[t * 3 + 0] = w1c[t * 3 + 0] * gs;
    s_w1f[t * 3 + 1] = w1c[t * 3 + 1] * gs;
    s_w1f[t * 3 + 2] = w1c[t * 3 + 2] * gs;
    s_b1f[t] = b1c[t] * gs + bb1[t];
  }
  if (t < 64) { float gs = g2[t] * BN_SCALE; s_be2[t] = b2c[t] * gs + bb2[t]; }
  if (t < 96) { float gs = g3[t] * BN_SCALE; s_be3[t] = b3c[t] * gs + bb3[t]; }
  __syncthreads();

  // ---- stage 1: conv1+bn+leaky+pool (fp32) -> scatter im2col into Bt2; fill w2a ----
  for (int idx = t; idx < 3072; idx += 256) {     // w2a[c][k] = w2c[c][k]*gs2[c]
    int c = idx / 48, k = idx - c * 48;
    w2a[c * 72 + k] = f2bf(w2c[idx] * (g2[c] * BN_SCALE));
  }
  for (int o = t; o < 16 * 186; o += 256) {
    const int c16 = o & 15;
    const int l = o >> 4;
    const int p = 2 * l;
    float m = -3.4e38f;
#pragma unroll
    for (int dc = 0; dc < 2; ++dc) {
      const int c = 2 * c16 + dc;
      const float u0 = s_w1f[c * 3 + 0], u1 = s_w1f[c * 3 + 1], u2 = s_w1f[c * 3 + 2];
      const float be = s_b1f[c];
#pragma unroll
      for (int dp = 0; dp < 2; ++dp) {
        float v = fmaf(sxf[p + dp], u0, fmaf(sxf[p + dp + 1], u1, fmaf(sxf[p + dp + 2], u2, be)));
        m = fmaxf(m, leaky(v));
      }
    }
    const unsigned short us = f2bf(m);
#pragma unroll
    for (int tap = 0; tap < 3; ++tap) {           // B[k=ci*3+tap][nout=l-tap]
      const int nn = l - tap;
      if (nn >= 0) bt2[nn * 72 + c16 * 3 + tap] = us;
    }
  }
  __syncthreads();

  // ---- conv2 MFMA: M=64 (4 m-tiles), N=192 (wave owns 3 n-tiles), K=48 (2 chunks) ----
  bf16x8 a2[4][2];
#pragma unroll
  for (int mt = 0; mt < 4; ++mt)
#pragma unroll
    for (int kc = 0; kc < 2; ++kc)
      a2[mt][kc] = *(const bf16x8*)(smem + 29184 + (mt * 16 + lr) * 144 + kc * 64 + quad * 16);

  f32x4 acc2[3][4];
#pragma unroll
  for (int nt = 0; nt < 3; ++nt)
#pragma unroll
    for (int mt = 0; mt < 4; ++mt)
#pragma unroll
      for (int r = 0; r < 4; ++r)
        acc2[nt][mt][r] = s_be2[mt * 16 + quad * 4 + r];

#pragma unroll
  for (int nt = 0; nt < 3; ++nt) {
    const int ntile = wv * 3 + nt;
    const char* rowp = smem + 1536 + (ntile * 16 + lr) * 144;
    bf16x8 b0 = *(const bf16x8*)(rowp + quad * 16);
    bf16x8 b1 = *(const bf16x8*)(rowp + 64 + quad * 16);
#pragma unroll
    for (int mt = 0; mt < 4; ++mt)
      acc2[nt][mt] = __builtin_amdgcn_mfma_f32_16x16x32_bf16(a2[mt][0], b0, acc2[nt][mt], 0, 0, 0);
#pragma unroll
    for (int mt = 0; mt < 4; ++mt)
      acc2[nt][mt] = __builtin_amdgcn_mfma_f32_16x16x32_bf16(a2[mt][1], b1, acc2[nt][mt], 0, 0, 0);
  }
  __syncthreads();

  // ---- phase C: zero Bt3, fill A3 (conv3 weights, bn folded) ----
  {
    float4 z4 = {0.f, 0.f, 0.f, 0.f};
    float4* z = (float4*)(smem);                  // Bt3 = 19968 B = 1248 float4
    for (int i = t; i < 1248; i += 256) z[i] = z4;
  }
  for (int idx = t; idx < 9216; idx += 256) {
    int c = idx / 96, k = idx - c * 96;
    a3s[c * 104 + k] = f2bf(w3c[idx] * (g3[c] * BN_SCALE));
  }
  __syncthreads();

  // ---- conv2 epilogue: leaky + 2x2 pool -> scatter im2col into Bt3 ----
#pragma unroll
  for (int nt = 0; nt < 3; ++nt) {
    const int ntile = wv * 3 + nt;
    const int nn0 = ntile * 16 + lr;              // conv2 output position
#pragma unroll
    for (int mt = 0; mt < 4; ++mt) {
      float o[4];
#pragma unroll
      for (int r = 0; r < 4; ++r) {
        float v = leaky(acc2[nt][mt][r]);
        o[r] = fmaxf(v, __shfl_xor(v, 1));        // position pair (adjacent lanes)
      }
      if ((lr & 1) == 0) {
        const int np = nn0 >> 1;                  // pooled position
        if (np <= 91) {
#pragma unroll
          for (int u = 0; u < 2; ++u) {
            const float pv = fmaxf(o[2 * u], o[2 * u + 1]);   // channel pair (reg pair)
            const int mp = mt * 8 + quad * 2 + u;             // pooled channel 0..31
            const unsigned short us = f2bf(pv);
#pragma unroll
            for (int tap = 0; tap < 3; ++tap) {
              const int rr = np - tap;
              if (rr >= 0) bt3[rr * 104 + mp * 3 + tap] = us;
            }
          }
        }
      }
    }
  }
  __syncthreads();

  // ---- conv3 MFMA: M=96, N=96, K=96; 36 tiles, wave owns 9 ----
  f32x4 acc3[9];
  {
    int mtPrev = -1;
    bf16x8 af[3];
#pragma unroll
    for (int s = 0; s < 9; ++s) {
      const int tt = wv * 9 + s;
      const int mt = tt / 6;
      const int ntile = tt - mt * 6;
      if (mt != mtPrev) {
#pragma unroll
        for (int kc = 0; kc < 3; ++kc)
          af[kc] = *(const bf16x8*)(smem + 19968 + (mt * 16 + lr) * 208 + kc * 64 + quad * 16);
        mtPrev = mt;
      }
      f32x4 acc;
#pragma unroll
      for (int r = 0; r < 4; ++r) acc[r] = s_be3[mt * 16 + quad * 4 + r];
#pragma unroll
      for (int kc = 0; kc < 3; ++kc) {
        bf16x8 b = *(const bf16x8*)(smem + (ntile * 16 + lr) * 208 + kc * 64 + quad * 16);
        acc = __builtin_amdgcn_mfma_f32_16x16x32_bf16(af[kc], b, acc, 0, 0, 0);
      }
      acc3[s] = acc;
    }
  }
  __syncthreads();

  // ---- conv3 epilogue: leaky + 2x2 pool -> s3f[ch*45+pos] fp32 ----
#pragma unroll
  for (int s = 0; s < 9; ++s) {
    const int tt = wv * 9 + s;
    const int mt = tt / 6;
    const int ntile = tt - mt * 6;
    const int nn0 = ntile * 16 + lr;
    float o[4];
#pragma unroll
    for (int r = 0; r < 4; ++r) {
      float v = leaky(acc3[s][r]);
      o[r] = fmaxf(v, __shfl_xor(v, 1));
    }
    if ((lr & 1) == 0) {
      const int np = nn0 >> 1;
      if (np <= 44) {
#pragma unroll
        for (int u = 0; u < 2; ++u) {
          const float pv = fmaxf(o[2 * u], o[2 * u + 1]);
          const int mp = mt * 8 + quad * 2 + u;   // pooled channel 0..47
          s3f[mp * 45 + np] = pv;
        }
      }
    }
  }
  __syncthreads();

  // ---- FC: 2160 -> 32 fp32 ----
  {
    const int j2 = t & 15;
    const int sI = t >> 4;
    const int k0 = sI * 135;
    float ax = 0.f, ay = 0.f;
#pragma unroll 4
    for (int i = 0; i < 135; ++i) {
      const int k = k0 + i;
      const float sv = s3f[k];
      const float2 w = *reinterpret_cast<const float2*>(fcw + k * 32 + 2 * j2);
      ax = fmaf(sv, w.x, ax);
      ay = fmaf(sv, w.y, ay);
    }
    s_part[sI * 32 + 2 * j2 + 0] = ax;
    s_part[sI * 32 + 2 * j2 + 1] = ay;
  }
  __syncthreads();
  if (t < 32) {
    float tot = fcb[t];
#pragma unroll
    for (int s = 0; s < 16; ++s) tot += s_part[s * 32 + t];
    feats[n * 32 + t] = tot;
  }
}

// ---------------------------------------------------------------------------
// Similarity MLP: one thread per (subject, pair) row; weights staged in LDS.
// ---------------------------------------------------------------------------
__global__ __launch_bounds__(256) void sim_kernel(
    const float* __restrict__ feats,
    const float* __restrict__ w1, const float* __restrict__ b1,
    const float* __restrict__ w2, const float* __restrict__ b2,
    const float* __restrict__ w3, const float* __restrict__ b3,
    const float* __restrict__ w4, const float* __restrict__ b4,
    float* __restrict__ subjects)
{
  __shared__ float sw1[64 * 32];
  __shared__ float sw2[32 * 16];
  __shared__ float sw3[16 * 8];
  __shared__ float sw4[8];
  __shared__ float sb1[32], sb2[16], sb3[8], sb4[1];

  const int t = threadIdx.x;
  for (int i = t; i < 2048; i += 256) sw1[i] = w1[i];
  for (int i = t; i < 512; i += 256) sw2[i] = w2[i];
  if (t < 128) sw3[t] = w3[t];
  if (t < 8) sw4[t] = w4[t];
  if (t < 32) sb1[t] = b1[t];
  if (t < 16) sb2[t] = b2[t];
  if (t < 8) sb3[t] = b3[t];
  if (t == 0) sb4[0] = b4[0];
  __syncthreads();

  const int idx = blockIdx.x * 256 + t;
  if (idx >= 30 * 9045) return;
  const int b = idx / 9045;
  const int p = idx - b * 9045;

  int i = (int)((269.0f - sqrtf((float)(72361 - 8 * p))) * 0.5f);
  i = max(0, min(133, i));
  while (134 * (i + 1) - ((i + 1) * i) / 2 <= p) ++i;
  while (134 * i - (i * (i - 1)) / 2 > p) --i;
  const int j = i + 1 + (p - (134 * i - (i * (i - 1)) / 2));

  const float4* f1 = reinterpret_cast<const float4*>(feats + (b * 135 + i) * 32);
  const float4* f2 = reinterpret_cast<const float4*>(feats + (b * 135 + j) * 32);
  float in[64];
#pragma unroll
  for (int q = 0; q < 8; ++q) {
    float4 v = f1[q];
    in[4 * q + 0] = v.x; in[4 * q + 1] = v.y; in[4 * q + 2] = v.z; in[4 * q + 3] = v.w;
  }
#pragma unroll
  for (int q = 0; q < 8; ++q) {
    float4 v = f2[q];
    in[32 + 4 * q + 0] = v.x; in[32 + 4 * q + 1] = v.y; in[32 + 4 * q + 2] = v.z; in[32 + 4 * q + 3] = v.w;
  }

  float h1[32];
#pragma unroll
  for (int jj = 0; jj < 32; ++jj) h1[jj] = sb1[jj];
#pragma unroll 8
  for (int ii = 0; ii < 64; ++ii) {
    const float av = in[ii];
    const float4* wr = reinterpret_cast<const float4*>(&sw1[ii * 32]);
#pragma unroll
    for (int r = 0; r < 8; ++r) {
      float4 w = wr[r];
      h1[4 * r + 0] = fmaf(av, w.x, h1[4 * r + 0]);
      h1[4 * r + 1] = fmaf(av, w.y, h1[4 * r + 1]);
      h1[4 * r + 2] = fmaf(av, w.z, h1[4 * r + 2]);
      h1[4 * r + 3] = fmaf(av, w.w, h1[4 * r + 3]);
    }
  }
#pragma unroll
  for (int jj = 0; jj < 32; ++jj) h1[jj] = fmaxf(h1[jj], 0.f);

  float h2[16];
#pragma unroll
  for (int jj = 0; jj < 16; ++jj) h2[jj] = sb2[jj];
#pragma unroll 8
  for (int ii = 0; ii < 32; ++ii) {
    const float av = h1[ii];
    const float4* wr = reinterpret_cast<const float4*>(&sw2[ii * 16]);
#pragma unroll
    for (int r = 0; r < 4; ++r) {
      float4 w = wr[r];
      h2[4 * r + 0] = fmaf(av, w.x, h2[4 * r + 0]);
      h2[4 * r + 1] = fmaf(av, w.y, h2[4 * r + 1]);
      h2[4 * r + 2] = fmaf(av, w.z, h2[4 * r + 2]);
      h2[4 * r + 3] = fmaf(av, w.w, h2[4 * r + 3]);
    }
  }
#pragma unroll
  for (int jj = 0; jj < 16; ++jj) h2[jj] = fmaxf(h2[jj], 0.f);

  float h3[8];
#pragma unroll
  for (int jj = 0; jj < 8; ++jj) h3[jj] = sb3[jj];
#pragma unroll
  for (int ii = 0; ii < 16; ++ii) {
    const float av = h2[ii];
    const float4* wr = reinterpret_cast<const float4*>(&sw3[ii * 8]);
#pragma unroll
    for (int r = 0; r < 2; ++r) {
      float4 w = wr[r];
      h3[4 * r + 0] = fmaf(av, w.x, h3[4 * r + 0]);
      h3[4 * r + 1] = fmaf(av, w.y, h3[4 * r + 1]);
      h3[4 * r + 2] = fmaf(av, w.z, h3[4 * r + 2]);
      h3[4 * r + 3] = fmaf(av, w.w, h3[4 * r + 3]);
    }
  }
#pragma unroll
  for (int jj = 0; jj < 8; ++jj) h3[jj] = fmaxf(h3[jj], 0.f);

  float z = sb4[0];
#pragma unroll
  for (int ii = 0; ii < 8; ++ii) z = fmaf(h3[ii], sw4[ii], z);

  float az = fabsf(z);
  float e = __expf(-2.f * az);
  float r = (1.f - e) / (1.f + e);
  subjects[idx] = copysignf(r, z);
}

// ---------------------------------------------------------------------------
// cls layer 1: 256 blocks = 64 k-chunks x 4 col-groups; subjects in LDS.
// ---------------------------------------------------------------------------
__global__ __launch_bounds__(256) void c1_kernel(
    const float* __restrict__ subjects,
    const float* __restrict__ w1,
    float* __restrict__ part)
{
  __shared__ float s_sub[30 * 142];
  const int q = blockIdx.x >> 2;
  const int g = blockIdx.x & 3;
  const int t = threadIdx.x;
  const int k0 = q * 142;
  const int nk = min(9045, k0 + 142) - k0;

  for (int idx = t; idx < 30 * nk; idx += 256) {
    const int r = idx / nk;
    const int kk = idx - r * nk;
    s_sub[r * 142 + kk] = subjects[r * 9045 + k0 + kk];
  }
  __syncthreads();

  const int col = g * 256 + t;
  float acc[30];
#pragma unroll
  for (int r = 0; r < 30; ++r) acc[r] = 0.f;
  for (int kk = 0; kk < nk; ++kk) {
    const float wv = w1[(size_t)(k0 + kk) * 1024 + col];
#pragma unroll
    for (int r = 0; r < 30; ++r) acc[r] = fmaf(s_sub[r * 142 + kk], wv, acc[r]);
  }
#pragma unroll
  for (int r = 0; r < 30; ++r) part[(q * 30 + r) * 1024 + col] = acc[r];
}

// ---------------------------------------------------------------------------
// cls tail A: reduce partials + rrelu + GEMM2 (1024->256) + relu -> act2.
// 120 blocks = 30 rows x 4 col-groups.
// ---------------------------------------------------------------------------
__global__ __launch_bounds__(256) void tail_a_kernel(
    const float* __restrict__ part,
    const float* __restrict__ cb1,
    const float* __restrict__ w2, const float* __restrict__ cb2,
    float* __restrict__ act2)
{
  __shared__ float sc1[1024];
  __shared__ float sp[256];
  const int r = blockIdx.x >> 2;
  const int cg = blockIdx.x & 3;
  const int t = threadIdx.x;

  for (int j = t; j < 1024; j += 256) {
    float s = cb1[j];
    for (int q = 0; q < 64; ++q) s += part[(q * 30 + r) * 1024 + j];
    sc1[j] = s >= 0.f ? s : RRELU_SLOPE * s;
  }
  __syncthreads();

  const int col = cg * 64 + (t & 63);
  const int ks = t >> 6;
  float acc = (ks == 0) ? cb2[col] : 0.f;
  const int kk0 = ks * 256;
#pragma unroll 4
  for (int kk = kk0; kk < kk0 + 256; ++kk)
    acc = fmaf(sc1[kk], w2[kk * 256 + col], acc);
  sp[t] = acc;
  __syncthreads();
  if (t < 64) {
    float s = sp[t] + sp[t + 64] + sp[t + 128] + sp[t + 192];
    act2[r * 256 + cg * 64 + t] = fmaxf(s, 0.f);
  }
}

// ---------------------------------------------------------------------------
// cls tail B: 256->64->3 + log_softmax. 30 blocks.
// ---------------------------------------------------------------------------
__global__ __launch_bounds__(256) void tail_b_kernel(
    const float* __restrict__ act2,
    const float* __restrict__ w3, const float* __restrict__ cb3,
    const float* __restrict__ w4, const float* __restrict__ cb4,
    float* __restrict__ out)
{
  __shared__ float sa[256];
  __shared__ float sc3[64];
  __shared__ float slg[3];
  const int r = blockIdx.x, t = threadIdx.x;

  sa[t] = act2[r * 256 + t];
  __syncthreads();
  if (t < 64) {
    float acc = cb3[t];
#pragma unroll 4
    for (int kk = 0; kk < 256; ++kk) acc = fmaf(sa[kk], w3[kk * 64 + t], acc);
    sc3[t] = fmaxf(acc, 0.f);
  }
  __syncthreads();
  if (t < 3) {
    float acc = cb4[t];
#pragma unroll
    for (int kk = 0; kk < 64; ++kk) acc = fmaf(sc3[kk], w4[kk * 3 + t], acc);
    slg[t] = acc;
  }
  __syncthreads();
  if (t == 0) {
    float m = fmaxf(slg[0], fmaxf(slg[1], slg[2]));
    float se = __expf(slg[0] - m) + __expf(slg[1] - m) + __expf(slg[2] - m);
    float lse = m + logf(se);
    out[r * 3 + 0] = slg[0] - lse;
    out[r * 3 + 1] = slg[1] - lse;
    out[r * 3 + 2] = slg[2] - lse;
  }
}

extern "C" void kernel_launch(void* const* d_in, const int* in_sizes, int n_in,
                              void* d_out, int out_size, void* d_ws, size_t ws_size,
                              hipStream_t stream) {
  const float* x    = (const float*)d_in[0];
  const float* w1c  = (const float*)d_in[1];
  const float* b1c  = (const float*)d_in[2];
  const float* g1   = (const float*)d_in[3];
  const float* bb1  = (const float*)d_in[4];
  const float* w2c  = (const float*)d_in[5];
  const float* b2c  = (const float*)d_in[6];
  const float* g2   = (const float*)d_in[7];
  const float* bb2  = (const float*)d_in[8];
  const float* w3c  = (const float*)d_in[9];
  const float* b3c  = (const float*)d_in[10];
  const float* g3   = (const float*)d_in[11];
  const float* bb3  = (const float*)d_in[12];
  const float* fcw  = (const float*)d_in[13];
  const float* fcb  = (const float*)d_in[14];
  const float* sw1  = (const float*)d_in[15];
  const float* sb1  = (const float*)d_in[16];
  const float* sw2  = (const float*)d_in[17];
  const float* sb2  = (const float*)d_in[18];
  const float* sw3  = (const float*)d_in[19];
  const float* sb3  = (const float*)d_in[20];
  const float* sw4  = (const float*)d_in[21];
  const float* sb4  = (const float*)d_in[22];
  const float* cw1  = (const float*)d_in[23];
  const float* cb1  = (const float*)d_in[24];
  const float* cw2  = (const float*)d_in[25];
  const float* cb2  = (const float*)d_in[26];
  const float* cw3  = (const float*)d_in[27];
  const float* cb3  = (const float*)d_in[28];
  const float* cw4  = (const float*)d_in[29];
  const float* cb4  = (const float*)d_in[30];

  float* ws = (float*)d_ws;
  float* feats    = ws;                 // 4050*32      = 129600 floats
  float* subjects = ws + 129600;        // 30*9045      = 271350 floats
  float* part     = ws + 401408;        // 64*30*1024   = 1966080 floats
  float* act2     = ws + 2367488;       // 30*256       = 7680 floats

  fe_kernel<<<4050, 256, 0, stream>>>(x, w1c, b1c, g1, bb1, w2c, b2c, g2, bb2,
                                      w3c, b3c, g3, bb3, fcw, fcb, feats);
  sim_kernel<<<1060, 256, 0, stream>>>(feats, sw1, sb1, sw2, sb2, sw3, sb3, sw4, sb4, subjects);
  c1_kernel<<<256, 256, 0, stream>>>(subjects, cw1, part);
  tail_a_kernel<<<120, 256, 0, stream>>>(part, cb1, cw2, cb2, act2);
  tail_b_kernel<<<30, 256, 0, stream>>>(act2, cw3, cb3, cw4, cb4, (float*)d_out);
}

// Round 4
// 419.389 us; speedup vs baseline: 3.4079x; 1.1047x over previous
//
#include <hip/hip_runtime.h>
#include <math.h>

#define BN_SCALE 0.99999500003749967f
#define RRELU_SLOPE 0.22916666666666666f

static __device__ __forceinline__ float leaky(float v) { return v > 0.f ? v : 0.01f * v; }

typedef __attribute__((ext_vector_type(8))) short bf16x8;
typedef __attribute__((ext_vector_type(4))) float f32x4;

static __device__ __forceinline__ unsigned short f2bf(float f) {
  unsigned u = __builtin_bit_cast(unsigned, f);
  u = (u + 0x7FFFu + ((u >> 16) & 1u)) >> 16;
  return (unsigned short)u;
}
static __device__ __forceinline__ float bflo(unsigned u) {
  return __builtin_bit_cast(float, u << 16);
}
static __device__ __forceinline__ float bfhi(unsigned u) {
  return __builtin_bit_cast(float, u & 0xFFFF0000u);
}

// ---------------------------------------------------------------------------
// prep: bn-fold + bf16 conv weights into MFMA A-fragment layout, fcw -> bf16.
// conv2 frag k-order: kc=0 -> k=(tap<<4)|ci (taps 0,1); kc=1 -> k<16: tap2, else 0.
// conv3 frag: tile (mt,tap), k = ci (0..31).
// ---------------------------------------------------------------------------
__global__ __launch_bounds__(256) void prep_kernel(
    const float* __restrict__ w2c, const float* __restrict__ g2,
    const float* __restrict__ w3c, const float* __restrict__ g3,
    const float* __restrict__ fcw,
    unsigned short* __restrict__ w2frag,
    unsigned short* __restrict__ w3frag,
    unsigned short* __restrict__ fcwb)
{
  const int item = blockIdx.x * 256 + threadIdx.x;
  if (item < 512) {                      // conv2 A-frags: 8 tiles x 64 lanes
    const int tile = item >> 6, lane = item & 63;
    const int mt = tile >> 1, kc = tile & 1;
    const int lr = lane & 15, quad = lane >> 4;
    const int c = mt * 16 + lr;
    const float gs = g2[c] * BN_SCALE;
#pragma unroll
    for (int j = 0; j < 8; ++j) {
      const int k = quad * 8 + j;
      float v;
      if (kc == 0) { const int tap = k >> 4, ci = k & 15; v = w2c[c * 48 + ci * 3 + tap] * gs; }
      else         { v = (k < 16) ? w2c[c * 48 + k * 3 + 2] * gs : 0.f; }
      w2frag[item * 8 + j] = f2bf(v);
    }
  } else if (item < 1664) {              // conv3 A-frags: 18 tiles x 64 lanes
    const int it = item - 512;
    const int tile = it >> 6, lane = it & 63;
    const int mt = tile / 3, tap = tile - mt * 3;
    const int lr = lane & 15, quad = lane >> 4;
    const int c = mt * 16 + lr;
    const float gs = g3[c] * BN_SCALE;
#pragma unroll
    for (int j = 0; j < 8; ++j) {
      const int ci = quad * 8 + j;
      w3frag[it * 8 + j] = f2bf(w3c[c * 96 + ci * 3 + tap] * gs);
    }
  } else if (item < 10304) {             // fcw -> bf16 (69120 = 8640*8)
    const int base = (item - 1664) * 8;
#pragma unroll
    for (int j = 0; j < 8; ++j) fcwb[base + j] = f2bf(fcw[base + j]);
  }
}

// ---------------------------------------------------------------------------
// Fused FeatureExtractor, tap-decomposed MFMA. One block per sequence.
// ---------------------------------------------------------------------------
__global__ __launch_bounds__(256) void fe_kernel(
    const float* __restrict__ x,
    const float* __restrict__ w1c, const float* __restrict__ b1c,
    const float* __restrict__ g1,  const float* __restrict__ bb1,
    const float* __restrict__ b2c, const float* __restrict__ g2, const float* __restrict__ bb2,
    const float* __restrict__ b3c, const float* __restrict__ g3, const float* __restrict__ bb3,
    const unsigned short* __restrict__ w2frag,
    const unsigned short* __restrict__ w3frag,
    const unsigned short* __restrict__ fcwb,
    const float* __restrict__ fcb,
    float* __restrict__ feats)
{
  __shared__ float sxf[376];
  __shared__ __align__(16) unsigned short s1t[208 * 16];  // [pos][16ch] bf16
  __shared__ __align__(16) unsigned short s2t[104 * 32];  // [pos][32ch] bf16
  __shared__ float s3f[2160];                             // [ch*45+pos] fp32
  __shared__ float s_w1f[96], s_b1f[32], s_be2[64], s_be3[96], s_part[512];

  const int t = threadIdx.x, n = blockIdx.x;
  const int wv = t >> 6, lane = t & 63, quad = lane >> 4, lr = lane & 15;

  // ---- early fragment loads (all global, L2-hot, latency hidden by phase A/B) ----
  bf16x8 a2[4][2];
#pragma unroll
  for (int mt = 0; mt < 4; ++mt)
#pragma unroll
    for (int kc = 0; kc < 2; ++kc)
      a2[mt][kc] = *(const bf16x8*)(w2frag + ((mt * 2 + kc) * 64 + lane) * 8);

  const int mtA = (wv * 9) / 6, mtB = (wv * 9 + 8) / 6;   // the 2 m-tiles this wave needs
  bf16x8 a3[2][3];
#pragma unroll
  for (int mi = 0; mi < 2; ++mi) {
    const int mt = mi ? mtB : mtA;
#pragma unroll
    for (int tap = 0; tap < 3; ++tap)
      a3[mi][tap] = *(const bf16x8*)(w3frag + ((mt * 3 + tap) * 64 + lane) * 8);
  }

  // ---- phase A: load x, zero pad rows, fold bn params ----
  for (int i = t; i < 375; i += 256) sxf[i] = x[n * 375 + i];
  if (t < 176) ((unsigned*)s1t)[1488 + t] = 0;   // rows 186..207
  if (t < 192) ((unsigned*)s2t)[1472 + t] = 0;   // rows 92..103
  if (t < 32) {
    const float gs = g1[t] * BN_SCALE;
    s_w1f[t * 3 + 0] = w1c[t * 3 + 0] * gs;
    s_w1f[t * 3 + 1] = w1c[t * 3 + 1] * gs;
    s_w1f[t * 3 + 2] = w1c[t * 3 + 2] * gs;
    s_b1f[t] = b1c[t] * gs + bb1[t];
  }
  if (t < 64) s_be2[t] = b2c[t] * (g2[t] * BN_SCALE) + bb2[t];
  if (t < 96) s_be3[t] = b3c[t] * (g3[t] * BN_SCALE) + bb3[t];
  __syncthreads();

  // ---- stage 1: conv1+bn+leaky+pool (fp32) -> s1t[pos][ch] bf16, b32 packed ----
  for (int o = t; o < 1488; o += 256) {
    const int cp = o & 7;          // channel-pair of pooled output
    const int l = o >> 3;          // pooled position 0..185
    const int p = 2 * l;
    const float x0 = sxf[p], x1 = sxf[p + 1], x2 = sxf[p + 2], x3 = sxf[p + 3];
    unsigned pk = 0;
#pragma unroll
    for (int u = 0; u < 2; ++u) {
      const int c16 = cp * 2 + u;
      float m = -3.4e38f;
#pragma unroll
      for (int dc = 0; dc < 2; ++dc) {
        const int c = 2 * c16 + dc;
        const float u0 = s_w1f[c * 3 + 0], u1 = s_w1f[c * 3 + 1], u2 = s_w1f[c * 3 + 2];
        const float be = s_b1f[c];
        const float v0 = fmaf(x0, u0, fmaf(x1, u1, fmaf(x2, u2, be)));
        const float v1 = fmaf(x1, u0, fmaf(x2, u1, fmaf(x3, u2, be)));
        m = fmaxf(m, fmaxf(leaky(v0), leaky(v1)));
      }
      pk |= (unsigned)f2bf(m) << (16 * u);
    }
    ((unsigned*)s1t)[l * 8 + cp] = pk;
  }
  __syncthreads();

  // ---- conv2 MFMA: M=64, N=192 (wave owns 3 n-tiles), taps via 2 MFMAs ----
  f32x4 acc2[3][4];
#pragma unroll
  for (int nt = 0; nt < 3; ++nt)
#pragma unroll
    for (int mt = 0; mt < 4; ++mt)
#pragma unroll
      for (int r = 0; r < 4; ++r)
        acc2[nt][mt][r] = s_be2[mt * 16 + quad * 4 + r];

#pragma unroll
  for (int nt = 0; nt < 3; ++nt) {
    const int nrow = (wv * 3 + nt) * 16 + lr;
    // kc=0: taps {0,1}: quad 0,1 -> tap0 ci {0-7,8-15}; quad 2,3 -> tap1
    bf16x8 b0 = *(const bf16x8*)(s1t + (nrow + (quad >> 1)) * 16 + (quad & 1) * 8);
    // kc=1: tap 2 (A zero for k>=16; quads 2,3 read finite tap2 data)
    bf16x8 b1 = *(const bf16x8*)(s1t + (nrow + 2) * 16 + (quad & 1) * 8);
#pragma unroll
    for (int mt = 0; mt < 4; ++mt)
      acc2[nt][mt] = __builtin_amdgcn_mfma_f32_16x16x32_bf16(a2[mt][0], b0, acc2[nt][mt], 0, 0, 0);
#pragma unroll
    for (int mt = 0; mt < 4; ++mt)
      acc2[nt][mt] = __builtin_amdgcn_mfma_f32_16x16x32_bf16(a2[mt][1], b1, acc2[nt][mt], 0, 0, 0);
  }

  // ---- conv2 epilogue: leaky+pool -> s2t[pos][ch] bf16 (no barrier: own acc, s2t disjoint) ----
#pragma unroll
  for (int nt = 0; nt < 3; ++nt) {
    const int nn0 = (wv * 3 + nt) * 16 + lr;
#pragma unroll
    for (int mt = 0; mt < 4; ++mt) {
      float o[4];
#pragma unroll
      for (int r = 0; r < 4; ++r) {
        const float v = leaky(acc2[nt][mt][r]);
        o[r] = fmaxf(v, __shfl_xor(v, 1));          // position pair
      }
      if ((lr & 1) == 0) {
        const int np = nn0 >> 1;
        if (np <= 91) {
          const float m0 = fmaxf(o[0], o[1]);       // channel pair (reg pair)
          const float m1 = fmaxf(o[2], o[3]);
          const unsigned pk = (unsigned)f2bf(m0) | ((unsigned)f2bf(m1) << 16);
          ((unsigned*)s2t)[np * 16 + mt * 4 + quad] = pk;
        }
      }
    }
  }
  __syncthreads();

  // ---- conv3 MFMA: M=96, N=96; 36 tiles, wave owns 9; 3 tap-MFMAs each ----
  f32x4 acc3[9];
#pragma unroll
  for (int s = 0; s < 9; ++s) {
    const int tt = wv * 9 + s;
    const int mt = tt / 6;
    const int ntile = tt - mt * 6;
    const int mi = (mt == mtA) ? 0 : 1;
    const int nrow = ntile * 16 + lr;
    f32x4 acc;
#pragma unroll
    for (int r = 0; r < 4; ++r) acc[r] = s_be3[mt * 16 + quad * 4 + r];
#pragma unroll
    for (int tap = 0; tap < 3; ++tap) {
      bf16x8 b = *(const bf16x8*)(s2t + (nrow + tap) * 32 + quad * 8);
      acc = __builtin_amdgcn_mfma_f32_16x16x32_bf16(a3[mi][tap], b, acc, 0, 0, 0);
    }
    acc3[s] = acc;
  }

  // ---- conv3 epilogue: leaky+pool -> s3f (separate array, no barrier needed) ----
#pragma unroll
  for (int s = 0; s < 9; ++s) {
    const int tt = wv * 9 + s;
    const int mt = tt / 6;
    const int ntile = tt - mt * 6;
    const int nn0 = ntile * 16 + lr;
    float o[4];
#pragma unroll
    for (int r = 0; r < 4; ++r) {
      const float v = leaky(acc3[s][r]);
      o[r] = fmaxf(v, __shfl_xor(v, 1));
    }
    if ((lr & 1) == 0) {
      const int np = nn0 >> 1;
      if (np <= 44) {
        const float m0 = fmaxf(o[0], o[1]);
        const float m1 = fmaxf(o[2], o[3]);
        const int mp = mt * 8 + quad * 2;
        s3f[mp * 45 + np] = m0;
        s3f[(mp + 1) * 45 + np] = m1;
      }
    }
  }
  __syncthreads();

  // ---- FC: 2160 -> 32, bf16 weights (dword = 2 cols) ----
  {
    const int j2 = t & 15;
    const int sI = t >> 4;
    const int k0 = sI * 135;
    float ax = 0.f, ay = 0.f;
#pragma unroll 4
    for (int i = 0; i < 135; ++i) {
      const int k = k0 + i;
      const float sv = s3f[k];
      const unsigned u = *(const unsigned*)(fcwb + k * 32 + 2 * j2);
      ax = fmaf(sv, bflo(u), ax);
      ay = fmaf(sv, bfhi(u), ay);
    }
    s_part[sI * 32 + 2 * j2 + 0] = ax;
    s_part[sI * 32 + 2 * j2 + 1] = ay;
  }
  __syncthreads();
  if (t < 32) {
    float tot = fcb[t];
#pragma unroll
    for (int s = 0; s < 16; ++s) tot += s_part[s * 32 + t];
    feats[n * 32 + t] = tot;
  }
}

// ---------------------------------------------------------------------------
// Similarity MLP: one thread per (subject, pair) row; weights staged in LDS.
// ---------------------------------------------------------------------------
__global__ __launch_bounds__(256) void sim_kernel(
    const float* __restrict__ feats,
    const float* __restrict__ w1, const float* __restrict__ b1,
    const float* __restrict__ w2, const float* __restrict__ b2,
    const float* __restrict__ w3, const float* __restrict__ b3,
    const float* __restrict__ w4, const float* __restrict__ b4,
    float* __restrict__ subjects)
{
  __shared__ float sw1[64 * 32];
  __shared__ float sw2[32 * 16];
  __shared__ float sw3[16 * 8];
  __shared__ float sw4[8];
  __shared__ float sb1[32], sb2[16], sb3[8], sb4[1];

  const int t = threadIdx.x;
  for (int i = t; i < 2048; i += 256) sw1[i] = w1[i];
  for (int i = t; i < 512; i += 256) sw2[i] = w2[i];
  if (t < 128) sw3[t] = w3[t];
  if (t < 8) sw4[t] = w4[t];
  if (t < 32) sb1[t] = b1[t];
  if (t < 16) sb2[t] = b2[t];
  if (t < 8) sb3[t] = b3[t];
  if (t == 0) sb4[0] = b4[0];
  __syncthreads();

  const int idx = blockIdx.x * 256 + t;
  if (idx >= 30 * 9045) return;
  const int b = idx / 9045;
  const int p = idx - b * 9045;

  int i = (int)((269.0f - sqrtf((float)(72361 - 8 * p))) * 0.5f);
  i = max(0, min(133, i));
  while (134 * (i + 1) - ((i + 1) * i) / 2 <= p) ++i;
  while (134 * i - (i * (i - 1)) / 2 > p) --i;
  const int j = i + 1 + (p - (134 * i - (i * (i - 1)) / 2));

  const float4* f1 = reinterpret_cast<const float4*>(feats + (b * 135 + i) * 32);
  const float4* f2 = reinterpret_cast<const float4*>(feats + (b * 135 + j) * 32);
  float in[64];
#pragma unroll
  for (int q = 0; q < 8; ++q) {
    float4 v = f1[q];
    in[4 * q + 0] = v.x; in[4 * q + 1] = v.y; in[4 * q + 2] = v.z; in[4 * q + 3] = v.w;
  }
#pragma unroll
  for (int q = 0; q < 8; ++q) {
    float4 v = f2[q];
    in[32 + 4 * q + 0] = v.x; in[32 + 4 * q + 1] = v.y; in[32 + 4 * q + 2] = v.z; in[32 + 4 * q + 3] = v.w;
  }

  float h1[32];
#pragma unroll
  for (int jj = 0; jj < 32; ++jj) h1[jj] = sb1[jj];
#pragma unroll 8
  for (int ii = 0; ii < 64; ++ii) {
    const float av = in[ii];
    const float4* wr = reinterpret_cast<const float4*>(&sw1[ii * 32]);
#pragma unroll
    for (int r = 0; r < 8; ++r) {
      float4 w = wr[r];
      h1[4 * r + 0] = fmaf(av, w.x, h1[4 * r + 0]);
      h1[4 * r + 1] = fmaf(av, w.y, h1[4 * r + 1]);
      h1[4 * r + 2] = fmaf(av, w.z, h1[4 * r + 2]);
      h1[4 * r + 3] = fmaf(av, w.w, h1[4 * r + 3]);
    }
  }
#pragma unroll
  for (int jj = 0; jj < 32; ++jj) h1[jj] = fmaxf(h1[jj], 0.f);

  float h2[16];
#pragma unroll
  for (int jj = 0; jj < 16; ++jj) h2[jj] = sb2[jj];
#pragma unroll 8
  for (int ii = 0; ii < 32; ++ii) {
    const float av = h1[ii];
    const float4* wr = reinterpret_cast<const float4*>(&sw2[ii * 16]);
#pragma unroll
    for (int r = 0; r < 4; ++r) {
      float4 w = wr[r];
      h2[4 * r + 0] = fmaf(av, w.x, h2[4 * r + 0]);
      h2[4 * r + 1] = fmaf(av, w.y, h2[4 * r + 1]);
      h2[4 * r + 2] = fmaf(av, w.z, h2[4 * r + 2]);
      h2[4 * r + 3] = fmaf(av, w.w, h2[4 * r + 3]);
    }
  }
#pragma unroll
  for (int jj = 0; jj < 16; ++jj) h2[jj] = fmaxf(h2[jj], 0.f);

  float h3[8];
#pragma unroll
  for (int jj = 0; jj < 8; ++jj) h3[jj] = sb3[jj];
#pragma unroll
  for (int ii = 0; ii < 16; ++ii) {
    const float av = h2[ii];
    const float4* wr = reinterpret_cast<const float4*>(&sw3[ii * 8]);
#pragma unroll
    for (int r = 0; r < 2; ++r) {
      float4 w = wr[r];
      h3[4 * r + 0] = fmaf(av, w.x, h3[4 * r + 0]);
      h3[4 * r + 1] = fmaf(av, w.y, h3[4 * r + 1]);
      h3[4 * r + 2] = fmaf(av, w.z, h3[4 * r + 2]);
      h3[4 * r + 3] = fmaf(av, w.w, h3[4 * r + 3]);
    }
  }
#pragma unroll
  for (int jj = 0; jj < 8; ++jj) h3[jj] = fmaxf(h3[jj], 0.f);

  float z = sb4[0];
#pragma unroll
  for (int ii = 0; ii < 8; ++ii) z = fmaf(h3[ii], sw4[ii], z);

  float az = fabsf(z);
  float e = __expf(-2.f * az);
  float r = (1.f - e) / (1.f + e);
  subjects[idx] = copysignf(r, z);
}

// ---------------------------------------------------------------------------
// cls layer 1: 256 blocks = 64 k-chunks x 4 col-groups; subjects in LDS.
// ---------------------------------------------------------------------------
__global__ __launch_bounds__(256) void c1_kernel(
    const float* __restrict__ subjects,
    const float* __restrict__ w1,
    float* __restrict__ part)
{
  __shared__ float s_sub[30 * 142];
  const int q = blockIdx.x >> 2;
  const int g = blockIdx.x & 3;
  const int t = threadIdx.x;
  const int k0 = q * 142;
  const int nk = min(9045, k0 + 142) - k0;

  for (int idx = t; idx < 30 * nk; idx += 256) {
    const int r = idx / nk;
    const int kk = idx - r * nk;
    s_sub[r * 142 + kk] = subjects[r * 9045 + k0 + kk];
  }
  __syncthreads();

  const int col = g * 256 + t;
  float acc[30];
#pragma unroll
  for (int r = 0; r < 30; ++r) acc[r] = 0.f;
  for (int kk = 0; kk < nk; ++kk) {
    const float wv = w1[(size_t)(k0 + kk) * 1024 + col];
#pragma unroll
    for (int r = 0; r < 30; ++r) acc[r] = fmaf(s_sub[r * 142 + kk], wv, acc[r]);
  }
#pragma unroll
  for (int r = 0; r < 30; ++r) part[(q * 30 + r) * 1024 + col] = acc[r];
}

// ---------------------------------------------------------------------------
// cls tail A: reduce partials + rrelu + GEMM2 (1024->256) + relu -> act2.
// ---------------------------------------------------------------------------
__global__ __launch_bounds__(256) void tail_a_kernel(
    const float* __restrict__ part,
    const float* __restrict__ cb1,
    const float* __restrict__ w2, const float* __restrict__ cb2,
    float* __restrict__ act2)
{
  __shared__ float sc1[1024];
  __shared__ float sp[256];
  const int r = blockIdx.x >> 2;
  const int cg = blockIdx.x & 3;
  const int t = threadIdx.x;

  for (int j = t; j < 1024; j += 256) {
    float s = cb1[j];
    for (int q = 0; q < 64; ++q) s += part[(q * 30 + r) * 1024 + j];
    sc1[j] = s >= 0.f ? s : RRELU_SLOPE * s;
  }
  __syncthreads();

  const int col = cg * 64 + (t & 63);
  const int ks = t >> 6;
  float acc = (ks == 0) ? cb2[col] : 0.f;
  const int kk0 = ks * 256;
#pragma unroll 4
  for (int kk = kk0; kk < kk0 + 256; ++kk)
    acc = fmaf(sc1[kk], w2[kk * 256 + col], acc);
  sp[t] = acc;
  __syncthreads();
  if (t < 64) {
    float s = sp[t] + sp[t + 64] + sp[t + 128] + sp[t + 192];
    act2[r * 256 + cg * 64 + t] = fmaxf(s, 0.f);
  }
}

// ---------------------------------------------------------------------------
// cls tail B: 256->64->3 + log_softmax. 30 blocks.
// ---------------------------------------------------------------------------
__global__ __launch_bounds__(256) void tail_b_kernel(
    const float* __restrict__ act2,
    const float* __restrict__ w3, const float* __restrict__ cb3,
    const float* __restrict__ w4, const float* __restrict__ cb4,
    float* __restrict__ out)
{
  __shared__ float sa[256];
  __shared__ float sc3[64];
  __shared__ float slg[3];
  const int r = blockIdx.x, t = threadIdx.x;

  sa[t] = act2[r * 256 + t];
  __syncthreads();
  if (t < 64) {
    float acc = cb3[t];
#pragma unroll 4
    for (int kk = 0; kk < 256; ++kk) acc = fmaf(sa[kk], w3[kk * 64 + t], acc);
    sc3[t] = fmaxf(acc, 0.f);
  }
  __syncthreads();
  if (t < 3) {
    float acc = cb4[t];
#pragma unroll
    for (int kk = 0; kk < 64; ++kk) acc = fmaf(sc3[kk], w4[kk * 3 + t], acc);
    slg[t] = acc;
  }
  __syncthreads();
  if (t == 0) {
    float m = fmaxf(slg[0], fmaxf(slg[1], slg[2]));
    float se = __expf(slg[0] - m) + __expf(slg[1] - m) + __expf(slg[2] - m);
    float lse = m + logf(se);
    out[r * 3 + 0] = slg[0] - lse;
    out[r * 3 + 1] = slg[1] - lse;
    out[r * 3 + 2] = slg[2] - lse;
  }
}

extern "C" void kernel_launch(void* const* d_in, const int* in_sizes, int n_in,
                              void* d_out, int out_size, void* d_ws, size_t ws_size,
                              hipStream_t stream) {
  const float* x    = (const float*)d_in[0];
  const float* w1c  = (const float*)d_in[1];
  const float* b1c  = (const float*)d_in[2];
  const float* g1   = (const float*)d_in[3];
  const float* bb1  = (const float*)d_in[4];
  const float* w2c  = (const float*)d_in[5];
  const float* b2c  = (const float*)d_in[6];
  const float* g2   = (const float*)d_in[7];
  const float* bb2  = (const float*)d_in[8];
  const float* w3c  = (const float*)d_in[9];
  const float* b3c  = (const float*)d_in[10];
  const float* g3   = (const float*)d_in[11];
  const float* bb3  = (const float*)d_in[12];
  const float* fcw  = (const float*)d_in[13];
  const float* fcb  = (const float*)d_in[14];
  const float* sw1  = (const float*)d_in[15];
  const float* sb1  = (const float*)d_in[16];
  const float* sw2  = (const float*)d_in[17];
  const float* sb2  = (const float*)d_in[18];
  const float* sw3  = (const float*)d_in[19];
  const float* sb3  = (const float*)d_in[20];
  const float* sw4  = (const float*)d_in[21];
  const float* sb4  = (const float*)d_in[22];
  const float* cw1  = (const float*)d_in[23];
  const float* cb1  = (const float*)d_in[24];
  const float* cw2  = (const float*)d_in[25];
  const float* cb2  = (const float*)d_in[26];
  const float* cw3  = (const float*)d_in[27];
  const float* cb3  = (const float*)d_in[28];
  const float* cw4  = (const float*)d_in[29];
  const float* cb4  = (const float*)d_in[30];

  float* ws = (float*)d_ws;
  float* feats    = ws;                 // 4050*32      = 129600 floats
  float* subjects = ws + 129600;        // 30*9045      = 271350 floats
  float* part     = ws + 401408;        // 64*30*1024   = 1966080 floats
  float* act2     = ws + 2367488;       // 30*256       = 7680 floats
  unsigned short* wsu = (unsigned short*)(ws + 2375168);
  unsigned short* w2frag = wsu;         // 4096 shorts
  unsigned short* w3frag = wsu + 4096;  // 9216 shorts
  unsigned short* fcwb   = wsu + 13312; // 69120 shorts

  prep_kernel<<<41, 256, 0, stream>>>(w2c, g2, w3c, g3, fcw, w2frag, w3frag, fcwb);
  fe_kernel<<<4050, 256, 0, stream>>>(x, w1c, b1c, g1, bb1, b2c, g2, bb2,
                                      b3c, g3, bb3, w2frag, w3frag, fcwb, fcb, feats);
  sim_kernel<<<1060, 256, 0, stream>>>(feats, sw1, sb1, sw2, sb2, sw3, sb3, sw4, sb4, subjects);
  c1_kernel<<<256, 256, 0, stream>>>(subjects, cw1, part);
  tail_a_kernel<<<120, 256, 0, stream>>>(part, cb1, cw2, cb2, act2);
  tail_b_kernel<<<30, 256, 0, stream>>>(act2, cw3, cb3, cw4, cb4, (float*)d_out);
}

// Round 5
// 406.540 us; speedup vs baseline: 3.5156x; 1.0316x over previous
//
#include <hip/hip_runtime.h>
#include <math.h>

#define BN_SCALE 0.99999500003749967f
#define RRELU_SLOPE 0.22916666666666666f

static __device__ __forceinline__ float leaky(float v) { return v > 0.f ? v : 0.01f * v; }

typedef __attribute__((ext_vector_type(8))) short bf16x8;
typedef __attribute__((ext_vector_type(4))) float f32x4;

static __device__ __forceinline__ unsigned short f2bf(float f) {
  unsigned u = __builtin_bit_cast(unsigned, f);
  u = (u + 0x7FFFu + ((u >> 16) & 1u)) >> 16;
  return (unsigned short)u;
}
static __device__ __forceinline__ float bflo(unsigned u) {
  return __builtin_bit_cast(float, u << 16);
}
static __device__ __forceinline__ float bfhi(unsigned u) {
  return __builtin_bit_cast(float, u & 0xFFFF0000u);
}

// ---------------------------------------------------------------------------
// prep: bn-fold + bf16 conv weights into MFMA A-fragment layout, fcw -> bf16.
// ---------------------------------------------------------------------------
__global__ __launch_bounds__(256) void prep_kernel(
    const float* __restrict__ w2c, const float* __restrict__ g2,
    const float* __restrict__ w3c, const float* __restrict__ g3,
    const float* __restrict__ fcw,
    unsigned short* __restrict__ w2frag,
    unsigned short* __restrict__ w3frag,
    unsigned short* __restrict__ fcwb)
{
  const int item = blockIdx.x * 256 + threadIdx.x;
  if (item < 512) {                      // conv2 A-frags: 8 tiles x 64 lanes
    const int tile = item >> 6, lane = item & 63;
    const int mt = tile >> 1, kc = tile & 1;
    const int lr = lane & 15, quad = lane >> 4;
    const int c = mt * 16 + lr;
    const float gs = g2[c] * BN_SCALE;
#pragma unroll
    for (int j = 0; j < 8; ++j) {
      const int k = quad * 8 + j;
      float v;
      if (kc == 0) { const int tap = k >> 4, ci = k & 15; v = w2c[c * 48 + ci * 3 + tap] * gs; }
      else         { v = (k < 16) ? w2c[c * 48 + k * 3 + 2] * gs : 0.f; }
      w2frag[item * 8 + j] = f2bf(v);
    }
  } else if (item < 1664) {              // conv3 A-frags: 18 tiles x 64 lanes
    const int it = item - 512;
    const int tile = it >> 6, lane = it & 63;
    const int mt = tile / 3, tap = tile - mt * 3;
    const int lr = lane & 15, quad = lane >> 4;
    const int c = mt * 16 + lr;
    const float gs = g3[c] * BN_SCALE;
#pragma unroll
    for (int j = 0; j < 8; ++j) {
      const int ci = quad * 8 + j;
      w3frag[it * 8 + j] = f2bf(w3c[c * 96 + ci * 3 + tap] * gs);
    }
  } else if (item < 10304) {             // fcw -> bf16 (69120 = 8640*8)
    const int base = (item - 1664) * 8;
#pragma unroll
    for (int j = 0; j < 8; ++j) fcwb[base + j] = f2bf(fcw[base + j]);
  }
}

// ---------------------------------------------------------------------------
// Fused FeatureExtractor, tap-decomposed MFMA, conflict-free LDS strides.
// s1t row stride = 24 shorts (48 B), s2t row stride = 40 shorts (80 B).
// ---------------------------------------------------------------------------
__global__ __launch_bounds__(256) void fe_kernel(
    const float* __restrict__ x,
    const float* __restrict__ w1c, const float* __restrict__ b1c,
    const float* __restrict__ g1,  const float* __restrict__ bb1,
    const float* __restrict__ b2c, const float* __restrict__ g2, const float* __restrict__ bb2,
    const float* __restrict__ b3c, const float* __restrict__ g3, const float* __restrict__ bb3,
    const unsigned short* __restrict__ w2frag,
    const unsigned short* __restrict__ w3frag,
    const unsigned short* __restrict__ fcwb,
    const float* __restrict__ fcb,
    float* __restrict__ feats)
{
  __shared__ float sxf[376];
  __shared__ __align__(16) unsigned short s1t[208 * 24];  // [pos][ch], stride 24
  __shared__ __align__(16) unsigned short s2t[104 * 40];  // [pos][ch], stride 40
  __shared__ float s3f[2160];                             // [ch*45+pos] fp32
  __shared__ float s_w1f[96], s_b1f[32], s_be2[64], s_be3[96], s_part[512];

  const int t = threadIdx.x, n = blockIdx.x;
  const int wv = t >> 6, lane = t & 63, quad = lane >> 4, lr = lane & 15;

  // ---- early fragment loads (global, L2-hot) ----
  bf16x8 a2[4][2];
#pragma unroll
  for (int mt = 0; mt < 4; ++mt)
#pragma unroll
    for (int kc = 0; kc < 2; ++kc)
      a2[mt][kc] = *(const bf16x8*)(w2frag + ((mt * 2 + kc) * 64 + lane) * 8);

  const int mtA = (wv * 9) / 6, mtB = (wv * 9 + 8) / 6;
  bf16x8 a3[2][3];
#pragma unroll
  for (int mi = 0; mi < 2; ++mi) {
    const int mt = mi ? mtB : mtA;
#pragma unroll
    for (int tap = 0; tap < 3; ++tap)
      a3[mi][tap] = *(const bf16x8*)(w3frag + ((mt * 3 + tap) * 64 + lane) * 8);
  }

  // ---- phase A: load x, zero pad rows, fold bn params ----
  for (int i = t; i < 375; i += 256) sxf[i] = x[n * 375 + i];
  if (t < 176) {                        // s1t rows 186..207, read-range dwords 0..7
    const int row = 186 + (t >> 3), d = t & 7;
    ((unsigned*)s1t)[row * 12 + d] = 0;
  }
  if (t < 192) {                        // s2t rows 92..103, read-range dwords 0..15
    const int row = 92 + (t >> 4), d = t & 15;
    ((unsigned*)s2t)[row * 20 + d] = 0;
  }
  if (t < 32) {
    const float gs = g1[t] * BN_SCALE;
    s_w1f[t * 3 + 0] = w1c[t * 3 + 0] * gs;
    s_w1f[t * 3 + 1] = w1c[t * 3 + 1] * gs;
    s_w1f[t * 3 + 2] = w1c[t * 3 + 2] * gs;
    s_b1f[t] = b1c[t] * gs + bb1[t];
  }
  if (t < 64) s_be2[t] = b2c[t] * (g2[t] * BN_SCALE) + bb2[t];
  if (t < 96) s_be3[t] = b3c[t] * (g3[t] * BN_SCALE) + bb3[t];
  __syncthreads();

  // ---- stage 1: conv1+bn+leaky+pool (fp32) -> s1t bf16 packed ----
  for (int o = t; o < 1488; o += 256) {
    const int cp = o & 7;
    const int l = o >> 3;
    const int p = 2 * l;
    const float x0 = sxf[p], x1 = sxf[p + 1], x2 = sxf[p + 2], x3 = sxf[p + 3];
    unsigned pk = 0;
#pragma unroll
    for (int u = 0; u < 2; ++u) {
      const int c16 = cp * 2 + u;
      float m = -3.4e38f;
#pragma unroll
      for (int dc = 0; dc < 2; ++dc) {
        const int c = 2 * c16 + dc;
        const float u0 = s_w1f[c * 3 + 0], u1 = s_w1f[c * 3 + 1], u2 = s_w1f[c * 3 + 2];
        const float be = s_b1f[c];
        const float v0 = fmaf(x0, u0, fmaf(x1, u1, fmaf(x2, u2, be)));
        const float v1 = fmaf(x1, u0, fmaf(x2, u1, fmaf(x3, u2, be)));
        m = fmaxf(m, fmaxf(leaky(v0), leaky(v1)));
      }
      pk |= (unsigned)f2bf(m) << (16 * u);
    }
    ((unsigned*)s1t)[l * 12 + cp] = pk;
  }
  __syncthreads();

  // ---- conv2 MFMA: M=64, N=192 (wave owns 3 n-tiles), 2 tap-MFMAs ----
  f32x4 acc2[3][4];
#pragma unroll
  for (int nt = 0; nt < 3; ++nt)
#pragma unroll
    for (int mt = 0; mt < 4; ++mt)
#pragma unroll
      for (int r = 0; r < 4; ++r)
        acc2[nt][mt][r] = s_be2[mt * 16 + quad * 4 + r];

#pragma unroll
  for (int nt = 0; nt < 3; ++nt) {
    const int nrow = (wv * 3 + nt) * 16 + lr;
    bf16x8 b0 = *(const bf16x8*)(s1t + (nrow + (quad >> 1)) * 24 + (quad & 1) * 8);
    bf16x8 b1 = *(const bf16x8*)(s1t + (nrow + 2) * 24 + (quad & 1) * 8);
#pragma unroll
    for (int mt = 0; mt < 4; ++mt)
      acc2[nt][mt] = __builtin_amdgcn_mfma_f32_16x16x32_bf16(a2[mt][0], b0, acc2[nt][mt], 0, 0, 0);
#pragma unroll
    for (int mt = 0; mt < 4; ++mt)
      acc2[nt][mt] = __builtin_amdgcn_mfma_f32_16x16x32_bf16(a2[mt][1], b1, acc2[nt][mt], 0, 0, 0);
  }

  // ---- conv2 epilogue: leaky+pool -> s2t bf16 ----
#pragma unroll
  for (int nt = 0; nt < 3; ++nt) {
    const int nn0 = (wv * 3 + nt) * 16 + lr;
#pragma unroll
    for (int mt = 0; mt < 4; ++mt) {
      float o[4];
#pragma unroll
      for (int r = 0; r < 4; ++r) {
        const float v = leaky(acc2[nt][mt][r]);
        o[r] = fmaxf(v, __shfl_xor(v, 1));
      }
      if ((lr & 1) == 0) {
        const int np = nn0 >> 1;
        if (np <= 91) {
          const float m0 = fmaxf(o[0], o[1]);
          const float m1 = fmaxf(o[2], o[3]);
          const unsigned pk = (unsigned)f2bf(m0) | ((unsigned)f2bf(m1) << 16);
          ((unsigned*)s2t)[np * 20 + mt * 4 + quad] = pk;
        }
      }
    }
  }
  __syncthreads();

  // ---- conv3 MFMA: M=96, N=96; 36 tiles, wave owns 9; 3 tap-MFMAs each ----
  f32x4 acc3[9];
#pragma unroll
  for (int s = 0; s < 9; ++s) {
    const int tt = wv * 9 + s;
    const int mt = tt / 6;
    const int ntile = tt - mt * 6;
    const int mi = (mt == mtA) ? 0 : 1;
    const int nrow = ntile * 16 + lr;
    f32x4 acc;
#pragma unroll
    for (int r = 0; r < 4; ++r) acc[r] = s_be3[mt * 16 + quad * 4 + r];
#pragma unroll
    for (int tap = 0; tap < 3; ++tap) {
      bf16x8 b = *(const bf16x8*)(s2t + (nrow + tap) * 40 + quad * 8);
      acc = __builtin_amdgcn_mfma_f32_16x16x32_bf16(a3[mi][tap], b, acc, 0, 0, 0);
    }
    acc3[s] = acc;
  }

  // ---- conv3 epilogue: leaky+pool -> s3f ----
#pragma unroll
  for (int s = 0; s < 9; ++s) {
    const int tt = wv * 9 + s;
    const int mt = tt / 6;
    const int ntile = tt - mt * 6;
    const int nn0 = ntile * 16 + lr;
    float o[4];
#pragma unroll
    for (int r = 0; r < 4; ++r) {
      const float v = leaky(acc3[s][r]);
      o[r] = fmaxf(v, __shfl_xor(v, 1));
    }
    if ((lr & 1) == 0) {
      const int np = nn0 >> 1;
      if (np <= 44) {
        const float m0 = fmaxf(o[0], o[1]);
        const float m1 = fmaxf(o[2], o[3]);
        const int mp = mt * 8 + quad * 2;
        s3f[mp * 45 + np] = m0;
        s3f[(mp + 1) * 45 + np] = m1;
      }
    }
  }
  __syncthreads();

  // ---- FC: 2160 -> 32, bf16 weights ----
  {
    const int j2 = t & 15;
    const int sI = t >> 4;
    const int k0 = sI * 135;
    float ax = 0.f, ay = 0.f;
#pragma unroll 4
    for (int i = 0; i < 135; ++i) {
      const int k = k0 + i;
      const float sv = s3f[k];
      const unsigned u = *(const unsigned*)(fcwb + k * 32 + 2 * j2);
      ax = fmaf(sv, bflo(u), ax);
      ay = fmaf(sv, bfhi(u), ay);
    }
    s_part[sI * 32 + 2 * j2 + 0] = ax;
    s_part[sI * 32 + 2 * j2 + 1] = ay;
  }
  __syncthreads();
  if (t < 32) {
    float tot = fcb[t];
#pragma unroll
    for (int s = 0; s < 16; ++s) tot += s_part[s * 32 + t];
    feats[n * 32 + t] = tot;
  }
}

// ---------------------------------------------------------------------------
// ga: Ga = feats @ W1[:32] + b1, Gb = feats @ W1[32:]. 8 rows/block.
// ---------------------------------------------------------------------------
__global__ __launch_bounds__(256) void ga_kernel(
    const float* __restrict__ feats,
    const float* __restrict__ w1, const float* __restrict__ b1,
    float* __restrict__ Ga, float* __restrict__ Gb)
{
  __shared__ float swa[1024], swb[1024], sb[32], sf[256];
  const int t = threadIdx.x;
  for (int i = t; i < 1024; i += 256) { swa[i] = w1[i]; swb[i] = w1[1024 + i]; }
  if (t < 32) sb[t] = b1[t];
  const int r0 = blockIdx.x * 8;
  const int fidx = r0 * 32 + t;
  sf[t] = (fidx < 129600) ? feats[fidx] : 0.f;
  __syncthreads();

  const int rl = t >> 5, j = t & 31;
  const int r = r0 + rl;
  if (r < 4050) {
    float ga = sb[j], gb = 0.f;
#pragma unroll 8
    for (int k = 0; k < 32; ++k) {
      const float f = sf[rl * 32 + k];
      ga = fmaf(f, swa[k * 32 + j], ga);
      gb = fmaf(f, swb[k * 32 + j], gb);
    }
    Ga[r * 32 + j] = ga;
    Gb[r * 32 + j] = gb;
  }
}

// ---------------------------------------------------------------------------
// Similarity MLP tail: h1 = relu(Ga[i]+Gb[j]); then 32->16->8->1 + tanh.
// ---------------------------------------------------------------------------
__global__ __launch_bounds__(256) void sim_kernel(
    const float* __restrict__ Ga, const float* __restrict__ Gb,
    const float* __restrict__ w2, const float* __restrict__ b2,
    const float* __restrict__ w3, const float* __restrict__ b3,
    const float* __restrict__ w4, const float* __restrict__ b4,
    float* __restrict__ subjects)
{
  __shared__ float sw2[512], sw3[128], sw4[8];
  __shared__ float sb2[16], sb3[8], sb4[1];

  const int t = threadIdx.x;
  for (int i = t; i < 512; i += 256) sw2[i] = w2[i];
  if (t < 128) sw3[t] = w3[t];
  if (t < 8) sw4[t] = w4[t];
  if (t < 16) sb2[t] = b2[t];
  if (t < 8) sb3[t] = b3[t];
  if (t == 0) sb4[0] = b4[0];
  __syncthreads();

  const int idx = blockIdx.x * 256 + t;
  if (idx >= 30 * 9045) return;
  const int b = idx / 9045;
  const int p = idx - b * 9045;

  int i = (int)((269.0f - sqrtf((float)(72361 - 8 * p))) * 0.5f);
  i = max(0, min(133, i));
  while (134 * (i + 1) - ((i + 1) * i) / 2 <= p) ++i;
  while (134 * i - (i * (i - 1)) / 2 > p) --i;
  const int j = i + 1 + (p - (134 * i - (i * (i - 1)) / 2));

  const float4* ga = reinterpret_cast<const float4*>(Ga + (b * 135 + i) * 32);
  const float4* gb = reinterpret_cast<const float4*>(Gb + (b * 135 + j) * 32);
  float h1[32];
#pragma unroll
  for (int q = 0; q < 8; ++q) {
    const float4 va = ga[q];
    const float4 vb = gb[q];
    h1[4 * q + 0] = fmaxf(va.x + vb.x, 0.f);
    h1[4 * q + 1] = fmaxf(va.y + vb.y, 0.f);
    h1[4 * q + 2] = fmaxf(va.z + vb.z, 0.f);
    h1[4 * q + 3] = fmaxf(va.w + vb.w, 0.f);
  }

  float h2[16];
#pragma unroll
  for (int jj = 0; jj < 16; ++jj) h2[jj] = sb2[jj];
#pragma unroll 8
  for (int ii = 0; ii < 32; ++ii) {
    const float av = h1[ii];
    const float4* wr = reinterpret_cast<const float4*>(&sw2[ii * 16]);
#pragma unroll
    for (int r = 0; r < 4; ++r) {
      float4 w = wr[r];
      h2[4 * r + 0] = fmaf(av, w.x, h2[4 * r + 0]);
      h2[4 * r + 1] = fmaf(av, w.y, h2[4 * r + 1]);
      h2[4 * r + 2] = fmaf(av, w.z, h2[4 * r + 2]);
      h2[4 * r + 3] = fmaf(av, w.w, h2[4 * r + 3]);
    }
  }
#pragma unroll
  for (int jj = 0; jj < 16; ++jj) h2[jj] = fmaxf(h2[jj], 0.f);

  float h3[8];
#pragma unroll
  for (int jj = 0; jj < 8; ++jj) h3[jj] = sb3[jj];
#pragma unroll
  for (int ii = 0; ii < 16; ++ii) {
    const float av = h2[ii];
    const float4* wr = reinterpret_cast<const float4*>(&sw3[ii * 8]);
#pragma unroll
    for (int r = 0; r < 2; ++r) {
      float4 w = wr[r];
      h3[4 * r + 0] = fmaf(av, w.x, h3[4 * r + 0]);
      h3[4 * r + 1] = fmaf(av, w.y, h3[4 * r + 1]);
      h3[4 * r + 2] = fmaf(av, w.z, h3[4 * r + 2]);
      h3[4 * r + 3] = fmaf(av, w.w, h3[4 * r + 3]);
    }
  }
#pragma unroll
  for (int jj = 0; jj < 8; ++jj) h3[jj] = fmaxf(h3[jj], 0.f);

  float z = sb4[0];
#pragma unroll
  for (int ii = 0; ii < 8; ++ii) z = fmaf(h3[ii], sw4[ii], z);

  float az = fabsf(z);
  float e = __expf(-2.f * az);
  float r = (1.f - e) / (1.f + e);
  subjects[idx] = copysignf(r, z);
}

// ---------------------------------------------------------------------------
// cls layer 1: 256 blocks = 64 k-chunks x 4 col-groups.
// subjects read via wave-uniform indices -> scalar loads (SMEM pipe).
// part layout: [r][q][col] for streaming tail reduce.
// ---------------------------------------------------------------------------
__global__ __launch_bounds__(256) void c1_kernel(
    const float* __restrict__ subjects,
    const float* __restrict__ w1,
    float* __restrict__ part)
{
  const int q = blockIdx.x >> 2;
  const int g = blockIdx.x & 3;
  const int t = threadIdx.x;
  const int k0 = q * 142;
  const int nk = min(9045, k0 + 142) - k0;
  const int col = g * 256 + t;

  float acc[30];
#pragma unroll
  for (int r = 0; r < 30; ++r) acc[r] = 0.f;

#pragma unroll 2
  for (int kk = 0; kk < nk; ++kk) {
    const int k = k0 + kk;
    const float w = w1[(size_t)k * 1024 + col];
#pragma unroll
    for (int r = 0; r < 30; ++r)
      acc[r] = fmaf(subjects[r * 9045 + k], w, acc[r]);
  }
#pragma unroll
  for (int r = 0; r < 30; ++r) part[(size_t)(r * 64 + q) * 1024 + col] = acc[r];
}

// ---------------------------------------------------------------------------
// cls tail A: reduce partials + rrelu + GEMM2 (1024->256) + relu -> act2.
// 120 blocks = 30 rows x 4 col-groups. part layout [r][q][col].
// ---------------------------------------------------------------------------
__global__ __launch_bounds__(256) void tail_a_kernel(
    const float* __restrict__ part,
    const float* __restrict__ cb1,
    const float* __restrict__ w2, const float* __restrict__ cb2,
    float* __restrict__ act2)
{
  __shared__ float sc1[1024];
  __shared__ float sp[256];
  const int r = blockIdx.x >> 2;
  const int cg = blockIdx.x & 3;
  const int t = threadIdx.x;

  for (int j = t; j < 1024; j += 256) {
    float s = cb1[j];
    const float* pp = part + (size_t)r * 64 * 1024 + j;
#pragma unroll 4
    for (int q = 0; q < 64; ++q) s += pp[q * 1024];
    sc1[j] = s >= 0.f ? s : RRELU_SLOPE * s;
  }
  __syncthreads();

  const int col = cg * 64 + (t & 63);
  const int ks = t >> 6;
  float acc = (ks == 0) ? cb2[col] : 0.f;
  const int kk0 = ks * 256;
  for (int kk = kk0; kk < kk0 + 256; kk += 4) {
    const float4 a = *reinterpret_cast<const float4*>(&sc1[kk]);
    acc = fmaf(a.x, w2[(kk + 0) * 256 + col], acc);
    acc = fmaf(a.y, w2[(kk + 1) * 256 + col], acc);
    acc = fmaf(a.z, w2[(kk + 2) * 256 + col], acc);
    acc = fmaf(a.w, w2[(kk + 3) * 256 + col], acc);
  }
  sp[t] = acc;
  __syncthreads();
  if (t < 64) {
    float s = sp[t] + sp[t + 64] + sp[t + 128] + sp[t + 192];
    act2[r * 256 + cg * 64 + t] = fmaxf(s, 0.f);
  }
}

// ---------------------------------------------------------------------------
// cls tail B: 256->64->3 + log_softmax. 30 blocks.
// ---------------------------------------------------------------------------
__global__ __launch_bounds__(256) void tail_b_kernel(
    const float* __restrict__ act2,
    const float* __restrict__ w3, const float* __restrict__ cb3,
    const float* __restrict__ w4, const float* __restrict__ cb4,
    float* __restrict__ out)
{
  __shared__ float sa[256];
  __shared__ float sc3[64];
  __shared__ float slg[3];
  const int r = blockIdx.x, t = threadIdx.x;

  sa[t] = act2[r * 256 + t];
  __syncthreads();
  if (t < 64) {
    float acc = cb3[t];
#pragma unroll 4
    for (int kk = 0; kk < 256; ++kk) acc = fmaf(sa[kk], w3[kk * 64 + t], acc);
    sc3[t] = fmaxf(acc, 0.f);
  }
  __syncthreads();
  if (t < 3) {
    float acc = cb4[t];
#pragma unroll
    for (int kk = 0; kk < 64; ++kk) acc = fmaf(sc3[kk], w4[kk * 3 + t], acc);
    slg[t] = acc;
  }
  __syncthreads();
  if (t == 0) {
    float m = fmaxf(slg[0], fmaxf(slg[1], slg[2]));
    float se = __expf(slg[0] - m) + __expf(slg[1] - m) + __expf(slg[2] - m);
    float lse = m + logf(se);
    out[r * 3 + 0] = slg[0] - lse;
    out[r * 3 + 1] = slg[1] - lse;
    out[r * 3 + 2] = slg[2] - lse;
  }
}

extern "C" void kernel_launch(void* const* d_in, const int* in_sizes, int n_in,
                              void* d_out, int out_size, void* d_ws, size_t ws_size,
                              hipStream_t stream) {
  const float* x    = (const float*)d_in[0];
  const float* w1c  = (const float*)d_in[1];
  const float* b1c  = (const float*)d_in[2];
  const float* g1   = (const float*)d_in[3];
  const float* bb1  = (const float*)d_in[4];
  const float* w2c  = (const float*)d_in[5];
  const float* b2c  = (const float*)d_in[6];
  const float* g2   = (const float*)d_in[7];
  const float* bb2  = (const float*)d_in[8];
  const float* w3c  = (const float*)d_in[9];
  const float* b3c  = (const float*)d_in[10];
  const float* g3   = (const float*)d_in[11];
  const float* bb3  = (const float*)d_in[12];
  const float* fcw  = (const float*)d_in[13];
  const float* fcb  = (const float*)d_in[14];
  const float* sw1  = (const float*)d_in[15];
  const float* sb1  = (const float*)d_in[16];
  const float* sw2  = (const float*)d_in[17];
  const float* sb2  = (const float*)d_in[18];
  const float* sw3  = (const float*)d_in[19];
  const float* sb3  = (const float*)d_in[20];
  const float* sw4  = (const float*)d_in[21];
  const float* sb4  = (const float*)d_in[22];
  const float* cw1  = (const float*)d_in[23];
  const float* cb1  = (const float*)d_in[24];
  const float* cw2  = (const float*)d_in[25];
  const float* cb2  = (const float*)d_in[26];
  const float* cw3  = (const float*)d_in[27];
  const float* cb3  = (const float*)d_in[28];
  const float* cw4  = (const float*)d_in[29];
  const float* cb4  = (const float*)d_in[30];

  float* ws = (float*)d_ws;
  float* feats    = ws;                  // 129600 floats
  float* subjects = ws + 129600;         // 271350 floats -> 400950
  float* part     = ws + 401408;         // 30*64*1024 = 1966080 -> 2367488
  float* act2     = ws + 2367488;        // 7680 -> 2375168
  float* Ga       = ws + 2375168;        // 129600 -> 2504768
  float* Gb       = ws + 2504768;        // 129600 -> 2634368
  unsigned short* wsu = (unsigned short*)(ws + 2634368);
  unsigned short* w2frag = wsu;          // 4096 shorts
  unsigned short* w3frag = wsu + 4096;   // 9216 shorts
  unsigned short* fcwb   = wsu + 13312;  // 69120 shorts

  prep_kernel<<<41, 256, 0, stream>>>(w2c, g2, w3c, g3, fcw, w2frag, w3frag, fcwb);
  fe_kernel<<<4050, 256, 0, stream>>>(x, w1c, b1c, g1, bb1, b2c, g2, bb2,
                                      b3c, g3, bb3, w2frag, w3frag, fcwb, fcb, feats);
  ga_kernel<<<507, 256, 0, stream>>>(feats, sw1, sb1, Ga, Gb);
  sim_kernel<<<1060, 256, 0, stream>>>(Ga, Gb, sw2, sb2, sw3, sb3, sw4, sb4, subjects);
  c1_kernel<<<256, 256, 0, stream>>>(subjects, cw1, part);
  tail_a_kernel<<<120, 256, 0, stream>>>(part, cb1, cw2, cb2, act2);
  tail_b_kernel<<<30, 256, 0, stream>>>(act2, cw3, cb3, cw4, cb4, (float*)d_out);
}

// Round 6
// 366.046 us; speedup vs baseline: 3.9046x; 1.1106x over previous
//
#include <hip/hip_runtime.h>
#include <math.h>

#define BN_SCALE 0.99999500003749967f
#define RRELU_SLOPE 0.22916666666666666f

static __device__ __forceinline__ float leaky(float v) { return v > 0.f ? v : 0.01f * v; }

typedef __attribute__((ext_vector_type(8))) short bf16x8;
typedef __attribute__((ext_vector_type(4))) float f32x4;

static __device__ __forceinline__ unsigned short f2bf(float f) {
  unsigned u = __builtin_bit_cast(unsigned, f);
  u = (u + 0x7FFFu + ((u >> 16) & 1u)) >> 16;
  return (unsigned short)u;
}
static __device__ __forceinline__ float bflo(unsigned u) {
  return __builtin_bit_cast(float, u << 16);
}
static __device__ __forceinline__ float bfhi(unsigned u) {
  return __builtin_bit_cast(float, u & 0xFFFF0000u);
}

// ---------------------------------------------------------------------------
// prep: bn-fold + bf16 conv weights into MFMA A-fragment layout,
// fcw -> transposed bf16 [32][2160].
// ---------------------------------------------------------------------------
__global__ __launch_bounds__(256) void prep_kernel(
    const float* __restrict__ w2c, const float* __restrict__ g2,
    const float* __restrict__ w3c, const float* __restrict__ g3,
    const float* __restrict__ fcw,
    unsigned short* __restrict__ w2frag,
    unsigned short* __restrict__ w3frag,
    unsigned short* __restrict__ fcwbT)
{
  const int item = blockIdx.x * 256 + threadIdx.x;
  if (item < 512) {                      // conv2 A-frags: 8 tiles x 64 lanes
    const int tile = item >> 6, lane = item & 63;
    const int mt = tile >> 1, kc = tile & 1;
    const int lr = lane & 15, quad = lane >> 4;
    const int c = mt * 16 + lr;
    const float gs = g2[c] * BN_SCALE;
#pragma unroll
    for (int j = 0; j < 8; ++j) {
      const int k = quad * 8 + j;
      float v;
      if (kc == 0) { const int tap = k >> 4, ci = k & 15; v = w2c[c * 48 + ci * 3 + tap] * gs; }
      else         { v = (k < 16) ? w2c[c * 48 + k * 3 + 2] * gs : 0.f; }
      w2frag[item * 8 + j] = f2bf(v);
    }
  } else if (item < 1664) {              // conv3 A-frags: 18 tiles x 64 lanes
    const int it = item - 512;
    const int tile = it >> 6, lane = it & 63;
    const int mt = tile / 3, tap = tile - mt * 3;
    const int lr = lane & 15, quad = lane >> 4;
    const int c = mt * 16 + lr;
    const float gs = g3[c] * BN_SCALE;
#pragma unroll
    for (int j = 0; j < 8; ++j) {
      const int ci = quad * 8 + j;
      w3frag[it * 8 + j] = f2bf(w3c[c * 96 + ci * 3 + tap] * gs);
    }
  } else if (item < 10304) {             // fcwT: 32 cols x 270 chunks of 8 k
    const int it = item - 1664;
    const int c = it / 270;
    const int ch = it - c * 270;
    const int k0 = ch * 8;
#pragma unroll
    for (int j = 0; j < 8; ++j)
      fcwbT[c * 2160 + k0 + j] = f2bf(fcw[(k0 + j) * 32 + c]);
  }
}

// ---------------------------------------------------------------------------
// fe: wave-autonomous. 1 wave = 1 sequence, NO barriers. Block=128 (2 waves,
// private 15136 B LDS arenas). conv1 fp32 -> s1t bf16; conv2/conv3 via
// tap-decomposed MFMA; s3 bf16 overlays dead s1t; FC in-wave (bf16 x bf16).
// ---------------------------------------------------------------------------
__global__ __launch_bounds__(128) void fe_kernel(
    const float* __restrict__ x,
    const float* __restrict__ w1c, const float* __restrict__ b1c,
    const float* __restrict__ g1,  const float* __restrict__ bb1,
    const float* __restrict__ b2c, const float* __restrict__ g2, const float* __restrict__ bb2,
    const float* __restrict__ b3c, const float* __restrict__ g3, const float* __restrict__ bb3,
    const unsigned short* __restrict__ w2frag,
    const unsigned short* __restrict__ w3frag,
    const unsigned short* __restrict__ fcwbT,
    const float* __restrict__ fcb,
    float* __restrict__ feats)
{
  __shared__ __align__(16) char smem[2 * 15136];
  const int t = threadIdx.x;
  const int wv = t >> 6, lane = t & 63, quad = lane >> 4, lr = lane & 15;
  const int n = blockIdx.x * 2 + wv;

  char* A = smem + wv * 15136;
  float* sxf = (float*)A;                             // 376 f (dead after stage1)
  unsigned short* s1t = (unsigned short*)(A + 1504);  // 194 rows x 16 ch
  unsigned short* s2t = (unsigned short*)(A + 7712);  // 98 rows x 32 ch
  unsigned short* s3b = (unsigned short*)A;           // 2160 bf16 (overlays sxf+s1t)
  float* w1f = (float*)(A + 13984);                   // 96
  float* b1f = (float*)(A + 14368);                   // 32
  float* be2 = (float*)(A + 14496);                   // 64
  float* be3 = (float*)(A + 14752);                   // 96

  // ---- conv2 A-frags from global (L2-hot) ----
  bf16x8 a2[4][2];
#pragma unroll
  for (int mt = 0; mt < 4; ++mt)
#pragma unroll
    for (int kc = 0; kc < 2; ++kc)
      a2[mt][kc] = *(const bf16x8*)(w2frag + ((mt * 2 + kc) * 64 + lane) * 8);

  // ---- per-wave tables + x load (no barrier: own-wave writes/reads) ----
  if (lane < 32) {
    const float gs = g1[lane] * BN_SCALE;
    w1f[lane * 3 + 0] = w1c[lane * 3 + 0] * gs;
    w1f[lane * 3 + 1] = w1c[lane * 3 + 1] * gs;
    w1f[lane * 3 + 2] = w1c[lane * 3 + 2] * gs;
    b1f[lane] = b1c[lane] * gs + bb1[lane];
  }
  be2[lane] = b2c[lane] * (g2[lane] * BN_SCALE) + bb2[lane];
  be3[lane] = b3c[lane] * (g3[lane] * BN_SCALE) + bb3[lane];
  if (lane < 32) be3[64 + lane] = b3c[64 + lane] * (g3[64 + lane] * BN_SCALE) + bb3[64 + lane];
  for (int i = lane; i < 375; i += 64) sxf[i] = x[n * 375 + i];

  // ---- stage 1: conv1+bn+leaky+pool -> s1t[pos][16] bf16 (rows 0..185) ----
  for (int o = lane; o < 1488; o += 64) {
    const int cp = o & 7;
    const int l = o >> 3;
    const int p = 2 * l;
    const float x0 = sxf[p], x1 = sxf[p + 1], x2 = sxf[p + 2], x3 = sxf[p + 3];
    unsigned pk = 0;
#pragma unroll
    for (int u = 0; u < 2; ++u) {
      const int c16 = cp * 2 + u;
      float m = -3.4e38f;
#pragma unroll
      for (int dc = 0; dc < 2; ++dc) {
        const int c = 2 * c16 + dc;
        const float u0 = w1f[c * 3 + 0], u1 = w1f[c * 3 + 1], u2 = w1f[c * 3 + 2];
        const float be = b1f[c];
        const float v0 = fmaf(x0, u0, fmaf(x1, u1, fmaf(x2, u2, be)));
        const float v1 = fmaf(x1, u0, fmaf(x2, u1, fmaf(x3, u2, be)));
        m = fmaxf(m, fmaxf(leaky(v0), leaky(v1)));
      }
      pk |= (unsigned)f2bf(m) << (16 * u);
    }
    ((unsigned*)s1t)[l * 8 + cp] = pk;
  }

  // ---- conv2: per n-tile: 2 tap-MFMAs x 4 m-tiles, epilogue -> s2t ----
#pragma unroll 2
  for (int nt = 0; nt < 12; ++nt) {
    const int nrow = nt * 16 + lr;
    bf16x8 b0 = *(const bf16x8*)(s1t + (nrow + (quad >> 1)) * 16 + (quad & 1) * 8);
    bf16x8 b1 = *(const bf16x8*)(s1t + (nrow + 2) * 16 + (quad & 1) * 8);
    f32x4 acc[4];
#pragma unroll
    for (int mt = 0; mt < 4; ++mt)
#pragma unroll
      for (int r = 0; r < 4; ++r) acc[mt][r] = be2[mt * 16 + quad * 4 + r];
#pragma unroll
    for (int mt = 0; mt < 4; ++mt)
      acc[mt] = __builtin_amdgcn_mfma_f32_16x16x32_bf16(a2[mt][0], b0, acc[mt], 0, 0, 0);
#pragma unroll
    for (int mt = 0; mt < 4; ++mt)
      acc[mt] = __builtin_amdgcn_mfma_f32_16x16x32_bf16(a2[mt][1], b1, acc[mt], 0, 0, 0);
#pragma unroll
    for (int mt = 0; mt < 4; ++mt) {
      float o[4];
#pragma unroll
      for (int r = 0; r < 4; ++r) {
        const float v = leaky(acc[mt][r]);
        o[r] = fmaxf(v, __shfl_xor(v, 1));          // position pair
      }
      if ((lr & 1) == 0) {
        const int np = nrow >> 1;
        if (np <= 91) {
          const float m0 = fmaxf(o[0], o[1]);       // channel pairs
          const float m1 = fmaxf(o[2], o[3]);
          const unsigned pk = (unsigned)f2bf(m0) | ((unsigned)f2bf(m1) << 16);
          ((unsigned*)s2t)[np * 16 + mt * 4 + quad] = pk;
        }
      }
    }
  }

  // ---- conv3: 6 m-tiles x 6 n-tiles x 3 tap-MFMAs, epilogue -> s3b bf16 ----
  for (int mt = 0; mt < 6; ++mt) {
    bf16x8 a3[3];
#pragma unroll
    for (int tap = 0; tap < 3; ++tap)
      a3[tap] = *(const bf16x8*)(w3frag + ((mt * 3 + tap) * 64 + lane) * 8);
#pragma unroll
    for (int nt = 0; nt < 6; ++nt) {
      const int nrow = nt * 16 + lr;
      f32x4 acc;
#pragma unroll
      for (int r = 0; r < 4; ++r) acc[r] = be3[mt * 16 + quad * 4 + r];
#pragma unroll
      for (int tap = 0; tap < 3; ++tap) {
        bf16x8 b = *(const bf16x8*)(s2t + (nrow + tap) * 32 + quad * 8);
        acc = __builtin_amdgcn_mfma_f32_16x16x32_bf16(a3[tap], b, acc, 0, 0, 0);
      }
      float o[4];
#pragma unroll
      for (int r = 0; r < 4; ++r) {
        const float v = leaky(acc[r]);
        o[r] = fmaxf(v, __shfl_xor(v, 1));
      }
      if ((lr & 1) == 0) {
        const int np = nrow >> 1;
        if (np <= 44) {
          const float m0 = fmaxf(o[0], o[1]);
          const float m1 = fmaxf(o[2], o[3]);
          const int mp = mt * 8 + quad * 2;
          s3b[mp * 45 + np] = f2bf(m0);
          s3b[(mp + 1) * 45 + np] = f2bf(m1);
        }
      }
    }
  }

  // ---- FC in-wave: lane=(col-pair j2, k-quarter ks); bf16 weights (T) ----
  {
    const int j2 = lane & 15, ks = lane >> 4;
    const int c0 = 2 * j2, c1 = c0 + 1;
    float a0 = 0.f, a1 = 0.f;
    for (int cch = ks; cch < 270; cch += 4) {
      const int k0 = cch * 8;
      const uint4 sv = *(const uint4*)(s3b + k0);
      const uint4 u0 = *(const uint4*)(fcwbT + c0 * 2160 + k0);
      const uint4 u1 = *(const uint4*)(fcwbT + c1 * 2160 + k0);
      float f[8] = {bflo(sv.x), bfhi(sv.x), bflo(sv.y), bfhi(sv.y),
                    bflo(sv.z), bfhi(sv.z), bflo(sv.w), bfhi(sv.w)};
      float g0[8] = {bflo(u0.x), bfhi(u0.x), bflo(u0.y), bfhi(u0.y),
                     bflo(u0.z), bfhi(u0.z), bflo(u0.w), bfhi(u0.w)};
      float g1[8] = {bflo(u1.x), bfhi(u1.x), bflo(u1.y), bfhi(u1.y),
                     bflo(u1.z), bfhi(u1.z), bflo(u1.w), bfhi(u1.w)};
#pragma unroll
      for (int j = 0; j < 8; ++j) {
        a0 = fmaf(f[j], g0[j], a0);
        a1 = fmaf(f[j], g1[j], a1);
      }
    }
    a0 += __shfl_xor(a0, 16); a0 += __shfl_xor(a0, 32);
    a1 += __shfl_xor(a1, 16); a1 += __shfl_xor(a1, 32);
    if (ks == 0) {
      float2 o2; o2.x = a0 + fcb[c0]; o2.y = a1 + fcb[c1];
      *reinterpret_cast<float2*>(feats + n * 32 + c0) = o2;
    }
  }
}

// ---------------------------------------------------------------------------
// ga: Ga = feats @ W1[:32] + b1, Gb = feats @ W1[32:]. 8 rows/block.
// ---------------------------------------------------------------------------
__global__ __launch_bounds__(256) void ga_kernel(
    const float* __restrict__ feats,
    const float* __restrict__ w1, const float* __restrict__ b1,
    float* __restrict__ Ga, float* __restrict__ Gb)
{
  __shared__ float swa[1024], swb[1024], sb[32], sf[256];
  const int t = threadIdx.x;
  for (int i = t; i < 1024; i += 256) { swa[i] = w1[i]; swb[i] = w1[1024 + i]; }
  if (t < 32) sb[t] = b1[t];
  const int r0 = blockIdx.x * 8;
  const int fidx = r0 * 32 + t;
  sf[t] = (fidx < 129600) ? feats[fidx] : 0.f;
  __syncthreads();

  const int rl = t >> 5, j = t & 31;
  const int r = r0 + rl;
  if (r < 4050) {
    float ga = sb[j], gb = 0.f;
#pragma unroll 8
    for (int k = 0; k < 32; ++k) {
      const float f = sf[rl * 32 + k];
      ga = fmaf(f, swa[k * 32 + j], ga);
      gb = fmaf(f, swb[k * 32 + j], gb);
    }
    Ga[r * 32 + j] = ga;
    Gb[r * 32 + j] = gb;
  }
}

// ---------------------------------------------------------------------------
// sim: 480 blocks = 30 subjects x 16 chunks. Ga/Gb of the subject staged in
// LDS (stride 36 -> conflict-free); h1=relu(Ga[i]+Gb[j]); 32->16->8->1+tanh.
// ---------------------------------------------------------------------------
__global__ __launch_bounds__(256) void sim_kernel(
    const float* __restrict__ Ga, const float* __restrict__ Gb,
    const float* __restrict__ w2, const float* __restrict__ b2,
    const float* __restrict__ w3, const float* __restrict__ b3,
    const float* __restrict__ w4, const float* __restrict__ b4,
    float* __restrict__ subjects)
{
  __shared__ float sGa[135 * 36];
  __shared__ float sGb[135 * 36];
  __shared__ float sw2[512], sw3[128], sw4[8];
  __shared__ float sb2[16], sb3[8], sb4v[1];

  const int t = threadIdx.x;
  const int b = blockIdx.x >> 4;
  const int c = blockIdx.x & 15;

  for (int i = t; i < 4320; i += 256) {
    const int r = i >> 5, col = i & 31;
    sGa[r * 36 + col] = Ga[b * 4320 + i];
    sGb[r * 36 + col] = Gb[b * 4320 + i];
  }
  for (int i = t; i < 512; i += 256) sw2[i] = w2[i];
  if (t < 128) sw3[t] = w3[t];
  if (t < 8) sw4[t] = w4[t];
  if (t < 16) sb2[t] = b2[t];
  if (t < 8) sb3[t] = b3[t];
  if (t == 0) sb4v[0] = b4[0];
  __syncthreads();

  const int pend = min(9045, (c + 1) * 566);
  for (int p = c * 566 + t; p < pend; p += 256) {
    int i = (int)((269.0f - sqrtf((float)(72361 - 8 * p))) * 0.5f);
    i = max(0, min(133, i));
    while (134 * (i + 1) - ((i + 1) * i) / 2 <= p) ++i;
    while (134 * i - (i * (i - 1)) / 2 > p) --i;
    const int j = i + 1 + (p - (134 * i - (i * (i - 1)) / 2));

    float h1[32];
#pragma unroll
    for (int q = 0; q < 8; ++q) {
      const float4 va = *(const float4*)(&sGa[i * 36 + 4 * q]);
      const float4 vb = *(const float4*)(&sGb[j * 36 + 4 * q]);
      h1[4 * q + 0] = fmaxf(va.x + vb.x, 0.f);
      h1[4 * q + 1] = fmaxf(va.y + vb.y, 0.f);
      h1[4 * q + 2] = fmaxf(va.z + vb.z, 0.f);
      h1[4 * q + 3] = fmaxf(va.w + vb.w, 0.f);
    }

    float h2[16];
#pragma unroll
    for (int jj = 0; jj < 16; ++jj) h2[jj] = sb2[jj];
#pragma unroll 8
    for (int ii = 0; ii < 32; ++ii) {
      const float av = h1[ii];
      const float4* wr = reinterpret_cast<const float4*>(&sw2[ii * 16]);
#pragma unroll
      for (int r = 0; r < 4; ++r) {
        float4 w = wr[r];
        h2[4 * r + 0] = fmaf(av, w.x, h2[4 * r + 0]);
        h2[4 * r + 1] = fmaf(av, w.y, h2[4 * r + 1]);
        h2[4 * r + 2] = fmaf(av, w.z, h2[4 * r + 2]);
        h2[4 * r + 3] = fmaf(av, w.w, h2[4 * r + 3]);
      }
    }
#pragma unroll
    for (int jj = 0; jj < 16; ++jj) h2[jj] = fmaxf(h2[jj], 0.f);

    float h3[8];
#pragma unroll
    for (int jj = 0; jj < 8; ++jj) h3[jj] = sb3[jj];
#pragma unroll
    for (int ii = 0; ii < 16; ++ii) {
      const float av = h2[ii];
      const float4* wr = reinterpret_cast<const float4*>(&sw3[ii * 8]);
#pragma unroll
      for (int r = 0; r < 2; ++r) {
        float4 w = wr[r];
        h3[4 * r + 0] = fmaf(av, w.x, h3[4 * r + 0]);
        h3[4 * r + 1] = fmaf(av, w.y, h3[4 * r + 1]);
        h3[4 * r + 2] = fmaf(av, w.z, h3[4 * r + 2]);
        h3[4 * r + 3] = fmaf(av, w.w, h3[4 * r + 3]);
      }
    }
#pragma unroll
    for (int jj = 0; jj < 8; ++jj) h3[jj] = fmaxf(h3[jj], 0.f);

    float z = sb4v[0];
#pragma unroll
    for (int ii = 0; ii < 8; ++ii) z = fmaf(h3[ii], sw4[ii], z);

    const float az = fabsf(z);
    const float e = __expf(-2.f * az);
    const float r = (1.f - e) / (1.f + e);
    subjects[b * 9045 + p] = copysignf(r, z);
  }
}

// ---------------------------------------------------------------------------
// cls layer 1: 512 blocks = 64 k-chunks x 8 col-groups of 128; 2 k-halves
// per block reduced via LDS. subjects loads wave-uniform -> scalar pipe.
// ---------------------------------------------------------------------------
__global__ __launch_bounds__(256) void c1_kernel(
    const float* __restrict__ subjects,
    const float* __restrict__ w1,
    float* __restrict__ part)
{
  __shared__ float red[30 * 128];
  const int q = blockIdx.x >> 3;
  const int g = blockIdx.x & 7;
  const int t = threadIdx.x;
  const int col = g * 128 + (t & 127);
  const int ks = t >> 7;
  const int k0 = q * 142;
  const int nk = min(9045, k0 + 142) - k0;
  const int half = (nk + 1) >> 1;
  const int ka = ks ? half : 0;
  const int kb = ks ? nk : half;

  float acc[30];
#pragma unroll
  for (int r = 0; r < 30; ++r) acc[r] = 0.f;

  for (int kk = ka; kk < kb; ++kk) {
    const int k = k0 + kk;
    const float w = w1[(size_t)k * 1024 + col];
#pragma unroll
    for (int r = 0; r < 30; ++r)
      acc[r] = fmaf(subjects[r * 9045 + k], w, acc[r]);
  }
  if (ks == 1) {
#pragma unroll
    for (int r = 0; r < 30; ++r) red[r * 128 + (t & 127)] = acc[r];
  }
  __syncthreads();
  if (ks == 0) {
#pragma unroll
    for (int r = 0; r < 30; ++r)
      part[(size_t)(r * 64 + q) * 1024 + col] = acc[r] + red[r * 128 + (t & 127)];
  }
}

// ---------------------------------------------------------------------------
// cls tail A: reduce partials + rrelu + GEMM2 (1024->256) + relu -> act2.
// 120 blocks = 30 rows x 4 col-groups. part layout [r][q][col].
// ---------------------------------------------------------------------------
__global__ __launch_bounds__(256) void tail_a_kernel(
    const float* __restrict__ part,
    const float* __restrict__ cb1,
    const float* __restrict__ w2, const float* __restrict__ cb2,
    float* __restrict__ act2)
{
  __shared__ float sc1[1024];
  __shared__ float sp[256];
  const int r = blockIdx.x >> 2;
  const int cg = blockIdx.x & 3;
  const int t = threadIdx.x;

  for (int j = t; j < 1024; j += 256) {
    float s = cb1[j];
    const float* pp = part + (size_t)r * 64 * 1024 + j;
#pragma unroll 4
    for (int q = 0; q < 64; ++q) s += pp[q * 1024];
    sc1[j] = s >= 0.f ? s : RRELU_SLOPE * s;
  }
  __syncthreads();

  const int col = cg * 64 + (t & 63);
  const int ks = t >> 6;
  float acc = (ks == 0) ? cb2[col] : 0.f;
  const int kk0 = ks * 256;
  for (int kk = kk0; kk < kk0 + 256; kk += 4) {
    const float4 a = *reinterpret_cast<const float4*>(&sc1[kk]);
    acc = fmaf(a.x, w2[(kk + 0) * 256 + col], acc);
    acc = fmaf(a.y, w2[(kk + 1) * 256 + col], acc);
    acc = fmaf(a.z, w2[(kk + 2) * 256 + col], acc);
    acc = fmaf(a.w, w2[(kk + 3) * 256 + col], acc);
  }
  sp[t] = acc;
  __syncthreads();
  if (t < 64) {
    float s = sp[t] + sp[t + 64] + sp[t + 128] + sp[t + 192];
    act2[r * 256 + cg * 64 + t] = fmaxf(s, 0.f);
  }
}

// ---------------------------------------------------------------------------
// cls tail B: 256->64->3 + log_softmax. 30 blocks.
// ---------------------------------------------------------------------------
__global__ __launch_bounds__(256) void tail_b_kernel(
    const float* __restrict__ act2,
    const float* __restrict__ w3, const float* __restrict__ cb3,
    const float* __restrict__ w4, const float* __restrict__ cb4,
    float* __restrict__ out)
{
  __shared__ float sa[256];
  __shared__ float sc3[64];
  __shared__ float slg[3];
  const int r = blockIdx.x, t = threadIdx.x;

  sa[t] = act2[r * 256 + t];
  __syncthreads();
  if (t < 64) {
    float acc = cb3[t];
#pragma unroll 4
    for (int kk = 0; kk < 256; ++kk) acc = fmaf(sa[kk], w3[kk * 64 + t], acc);
    sc3[t] = fmaxf(acc, 0.f);
  }
  __syncthreads();
  if (t < 3) {
    float acc = cb4[t];
#pragma unroll
    for (int kk = 0; kk < 64; ++kk) acc = fmaf(sc3[kk], w4[kk * 3 + t], acc);
    slg[t] = acc;
  }
  __syncthreads();
  if (t == 0) {
    float m = fmaxf(slg[0], fmaxf(slg[1], slg[2]));
    float se = __expf(slg[0] - m) + __expf(slg[1] - m) + __expf(slg[2] - m);
    float lse = m + logf(se);
    out[r * 3 + 0] = slg[0] - lse;
    out[r * 3 + 1] = slg[1] - lse;
    out[r * 3 + 2] = slg[2] - lse;
  }
}

extern "C" void kernel_launch(void* const* d_in, const int* in_sizes, int n_in,
                              void* d_out, int out_size, void* d_ws, size_t ws_size,
                              hipStream_t stream) {
  const float* x    = (const float*)d_in[0];
  const float* w1c  = (const float*)d_in[1];
  const float* b1c  = (const float*)d_in[2];
  const float* g1   = (const float*)d_in[3];
  const float* bb1  = (const float*)d_in[4];
  const float* w2c  = (const float*)d_in[5];
  const float* b2c  = (const float*)d_in[6];
  const float* g2   = (const float*)d_in[7];
  const float* bb2  = (const float*)d_in[8];
  const float* w3c  = (const float*)d_in[9];
  const float* b3c  = (const float*)d_in[10];
  const float* g3   = (const float*)d_in[11];
  const float* bb3  = (const float*)d_in[12];
  const float* fcw  = (const float*)d_in[13];
  const float* fcb  = (const float*)d_in[14];
  const float* sw1  = (const float*)d_in[15];
  const float* sb1  = (const float*)d_in[16];
  const float* sw2  = (const float*)d_in[17];
  const float* sb2  = (const float*)d_in[18];
  const float* sw3  = (const float*)d_in[19];
  const float* sb3  = (const float*)d_in[20];
  const float* sw4  = (const float*)d_in[21];
  const float* sb4  = (const float*)d_in[22];
  const float* cw1  = (const float*)d_in[23];
  const float* cb1  = (const float*)d_in[24];
  const float* cw2  = (const float*)d_in[25];
  const float* cb2  = (const float*)d_in[26];
  const float* cw3  = (const float*)d_in[27];
  const float* cb3  = (const float*)d_in[28];
  const float* cw4  = (const float*)d_in[29];
  const float* cb4  = (const float*)d_in[30];

  float* ws = (float*)d_ws;
  float* feats    = ws;                  // 129600 floats
  float* subjects = ws + 129600;         // 271350 -> 400950
  float* part     = ws + 401408;         // 30*64*1024 = 1966080 -> 2367488
  float* act2     = ws + 2367488;        // 7680 -> 2375168
  float* Ga       = ws + 2375168;        // 129600 -> 2504768
  float* Gb       = ws + 2504768;        // 129600 -> 2634368
  unsigned short* wsu = (unsigned short*)(ws + 2634368);
  unsigned short* w2frag = wsu;          // 4096 shorts
  unsigned short* w3frag = wsu + 4096;   // 9216 shorts
  unsigned short* fcwbT  = wsu + 13312;  // 69120 shorts

  prep_kernel<<<41, 256, 0, stream>>>(w2c, g2, w3c, g3, fcw, w2frag, w3frag, fcwbT);
  fe_kernel<<<2025, 128, 0, stream>>>(x, w1c, b1c, g1, bb1, b2c, g2, bb2,
                                      b3c, g3, bb3, w2frag, w3frag, fcwbT, fcb, feats);
  ga_kernel<<<507, 256, 0, stream>>>(feats, sw1, sb1, Ga, Gb);
  sim_kernel<<<480, 256, 0, stream>>>(Ga, Gb, sw2, sb2, sw3, sb3, sw4, sb4, subjects);
  c1_kernel<<<512, 256, 0, stream>>>(subjects, cw1, part);
  tail_a_kernel<<<120, 256, 0, stream>>>(part, cb1, cw2, cb2, act2);
  tail_b_kernel<<<30, 256, 0, stream>>>(act2, cw3, cb3, cw4, cb4, (float*)d_out);
}